// Round 2
// baseline (464.827 us; speedup 1.0000x reference)
//
#include <hip/hip_runtime.h>
#include <cstdint>
#include <cstddef>

typedef __bf16 bf16;
typedef __bf16 bf16x4 __attribute__((ext_vector_type(4)));
typedef __bf16 bf16x8 __attribute__((ext_vector_type(8)));
typedef float f32x4 __attribute__((ext_vector_type(4)));
typedef float f32x16 __attribute__((ext_vector_type(16)));
typedef unsigned int uint2v __attribute__((ext_vector_type(2)));

#define SLD 40  // GEMM LDS row stride (elements): 80B -> 2-way (free) bank pattern

// ---------------------------------------------------------------------------
// permlane32_swap helpers (attn softmax cross-half exchange)
// ---------------------------------------------------------------------------
__device__ __forceinline__ void plswap(unsigned& a, unsigned& b) {
  uint2v r = __builtin_amdgcn_permlane32_swap(a, b, false, false);
  a = r[0];
  b = r[1];
}
__device__ __forceinline__ float xhalf_max(float x) {
  unsigned a = __float_as_uint(x), b = a;
  plswap(a, b);
  return fmaxf(__uint_as_float(a), __uint_as_float(b));
}
__device__ __forceinline__ float xhalf_sum(float x) {
  unsigned a = __float_as_uint(x), b = a;
  plswap(a, b);
  return __uint_as_float(a) + __uint_as_float(b);
}
__device__ __forceinline__ unsigned cvtpk(float lo, float hi) {
  unsigned r;
  asm("v_cvt_pk_bf16_f32 %0, %1, %2" : "=v"(r) : "v"(lo), "v"(hi));
  return r;
}

// Build one PV B-fragment (P^T[k][q], k-chunk of 16) from 8 f32 P values.
// X reg i holds k = 8*(i>>2) + (i&3) + 4*hi for this lane (32x32 C layout).
template <int G0>
__device__ __forceinline__ bf16x8 build_pfrag(const f32x16& X) {
  unsigned a0 = cvtpk(X[G0 * 4 + 0], X[G0 * 4 + 1]);
  unsigned b0 = cvtpk(X[G0 * 4 + 4], X[G0 * 4 + 5]);
  plswap(a0, b0);
  unsigned a1 = cvtpk(X[G0 * 4 + 2], X[G0 * 4 + 3]);
  unsigned b1 = cvtpk(X[G0 * 4 + 6], X[G0 * 4 + 7]);
  plswap(a1, b1);
  union {
    unsigned w[4];
    bf16x8 v;
  } u;
  u.w[0] = a0;
  u.w[1] = a1;
  u.w[2] = b0;
  u.w[3] = b1;
  return u.v;
}

// ---------------------------------------------------------------------------
// Fused QKV projection: one dispatch, grid (512, 3); blockIdx.y = slice.
// C[M=1024, N=8192] = X[1024,1024] @ W[8192,1024]^T + bias, f32 in, bf16 out.
// 128x128 tile, BK=32, 4 waves (2x2). Async stage split: next K-tile's global
// loads are issued into regs BEFORE the MFMA phase, written to LDS after the
// barrier (T14) -> HBM latency hides under compute.
// Scatter layouts:
//   slice 0 (Q): [bh][t][d],  t  = s*8 + c      (canonical query order)
//   slice 1 (K): [bh][k''][d], k'' = c*256 + s  (permuted key order)
//   slice 2 (V): [bh][d][k''] (V^T, permuted)   -> bf16x4 vectorized stores
// Key permutation is legal: online softmax is permutation-invariant over the
// key axis as long as K and V use the SAME order; attn consumes storage order.
// ---------------------------------------------------------------------------
__global__ __launch_bounds__(256, 4)
void qkv_proj(const float* __restrict__ Xq, const float* __restrict__ Xk,
              const float* __restrict__ Xv, const float* __restrict__ Wq,
              const float* __restrict__ Wk, const float* __restrict__ Wv,
              const float* __restrict__ Bq, const float* __restrict__ Bk,
              const float* __restrict__ Bv, bf16* __restrict__ Qo,
              bf16* __restrict__ Ko, bf16* __restrict__ Vo, float qsc) {
  __shared__ bf16 As[128 * SLD];
  __shared__ bf16 Bs[128 * SLD];
  const int slice = blockIdx.y;
  const float* A = (slice == 0) ? Xq : (slice == 1) ? Xk : Xv;
  const float* W = (slice == 0) ? Wq : (slice == 1) ? Wk : Wv;
  const float* bias = (slice == 0) ? Bq : (slice == 1) ? Bk : Bv;

  const int tid = threadIdx.x;
  const int w = tid >> 6, l = tid & 63;
  const int l15 = l & 15, quad = l >> 4;
  const int tm = (blockIdx.x >> 6) << 7;  // tiles_n = 64
  const int tn = (blockIdx.x & 63) << 7;
  const int wm = (w >> 1) << 6;
  const int wn = (w & 1) << 6;

  const int frow = tid >> 1;
  const int fch = (tid & 1) * 16;

  f32x4 acc[4][4] = {};
  f32x4 ar[4], br[4];

  auto load_regs = [&](int k0) {
    const float* sA = A + (size_t)(tm + frow) * 1024 + k0 + fch;
    ar[0] = *(const f32x4*)(sA);
    ar[1] = *(const f32x4*)(sA + 4);
    ar[2] = *(const f32x4*)(sA + 8);
    ar[3] = *(const f32x4*)(sA + 12);
    const float* sB = W + (size_t)(tn + frow) * 1024 + k0 + fch;
    br[0] = *(const f32x4*)(sB);
    br[1] = *(const f32x4*)(sB + 4);
    br[2] = *(const f32x4*)(sB + 8);
    br[3] = *(const f32x4*)(sB + 12);
  };
  auto write_lds = [&]() {
    bf16x8 y0, y1;
#pragma unroll
    for (int j = 0; j < 4; ++j) {
      y0[j] = (bf16)ar[0][j]; y0[j + 4] = (bf16)ar[1][j];
      y1[j] = (bf16)ar[2][j]; y1[j + 4] = (bf16)ar[3][j];
    }
    *(bf16x8*)(As + frow * SLD + fch) = y0;
    *(bf16x8*)(As + frow * SLD + fch + 8) = y1;
#pragma unroll
    for (int j = 0; j < 4; ++j) {
      y0[j] = (bf16)br[0][j]; y0[j + 4] = (bf16)br[1][j];
      y1[j] = (bf16)br[2][j]; y1[j + 4] = (bf16)br[3][j];
    }
    *(bf16x8*)(Bs + frow * SLD + fch) = y0;
    *(bf16x8*)(Bs + frow * SLD + fch + 8) = y1;
  };

  load_regs(0);
  write_lds();
  __syncthreads();

  for (int k0 = 0; k0 < 1024; k0 += 32) {
    const bool more = (k0 + 32) < 1024;
    if (more) load_regs(k0 + 32);  // issue early; lands under MFMA

    bf16x8 af[4], bfr[4];
#pragma unroll
    for (int i = 0; i < 4; ++i)
      af[i] = *(const bf16x8*)(As + (wm + i * 16 + l15) * SLD + quad * 8);
#pragma unroll
    for (int j = 0; j < 4; ++j)
      bfr[j] = *(const bf16x8*)(Bs + (wn + j * 16 + l15) * SLD + quad * 8);
#pragma unroll
    for (int i = 0; i < 4; ++i)
#pragma unroll
      for (int j = 0; j < 4; ++j)
        acc[i][j] = __builtin_amdgcn_mfma_f32_16x16x32_bf16(af[i], bfr[j], acc[i][j], 0, 0, 0);

    __syncthreads();
    if (more) {
      write_lds();
      __syncthreads();
    }
  }

  if (slice == 2) {
    // V^T scatter, vectorized: consecutive r -> consecutive k''.
#pragma unroll
    for (int i = 0; i < 4; ++i) {
#pragma unroll
      for (int j = 0; j < 4; ++j) {
        const int n = tn + wn + j * 16 + l15;
        const int d = n & 127, h = (n >> 7) & 7, c = n >> 10;
        const float bv = bias[n];
        const int m0 = tm + wm + i * 16 + quad * 4;
        const int b = m0 >> 8, s0 = m0 & 255;
        const size_t idx = ((size_t)((b * 8 + h) * 128 + d)) * 2048 + (c << 8) + s0;
        bf16x4 ov;
#pragma unroll
        for (int r = 0; r < 4; ++r) ov[r] = (bf16)(acc[i][j][r] + bv);
        *(bf16x4*)(Vo + idx) = ov;
      }
    }
  } else {
    bf16* O = slice ? Ko : Qo;
    const float osc = slice ? 1.0f : qsc;
#pragma unroll
    for (int i = 0; i < 4; ++i) {
#pragma unroll
      for (int j = 0; j < 4; ++j) {
        const int n = tn + wn + j * 16 + l15;
        const int d = n & 127, h = (n >> 7) & 7, c = n >> 10;
        const float bv = bias[n];
#pragma unroll
        for (int r = 0; r < 4; ++r) {
          const int m = tm + wm + i * 16 + quad * 4 + r;
          const int b = m >> 8, s = m & 255;
          const int row = slice ? ((c << 8) | s) : ((s << 3) | c);
          const size_t idx = ((size_t)(b * 8 + h) * 2048 + row) * 128 + d;
          O[idx] = (bf16)((acc[i][j][r] + bv) * osc);
        }
      }
    }
  }
}

// ---------------------------------------------------------------------------
// NT GEMM for the output projection (split-K). C[M,N] = A[M,K] @ B[N,K]^T.
// MODE 3: blockIdx.y owns a 1024-wide K-slice, writes f32 partial (no bias)
// at C + blockIdx.y*M*N. A bf16, B f32. Async stage split as above.
// ---------------------------------------------------------------------------
template <int MODE, bool A_F32, bool B_F32, typename CT>
__global__ __launch_bounds__(256, 4)
void gemm_nt(const void* __restrict__ Ap, const void* __restrict__ Bp,
             const float* __restrict__ bias, CT* __restrict__ C,
             int M, int N, int K, float oscale) {
  __shared__ bf16 As[128 * SLD];
  __shared__ bf16 Bs[128 * SLD];
  const int tid = threadIdx.x;
  const int w = tid >> 6, l = tid & 63;
  const int l15 = l & 15, quad = l >> 4;
  const int tiles_n = N >> 7;
  const int tm = (blockIdx.x / tiles_n) << 7;
  const int tn = (blockIdx.x % tiles_n) << 7;
  const int wm = (w >> 1) << 6;
  const int wn = (w & 1) << 6;

  f32x4 acc[4][4] = {};

  const int frow = tid >> 1;
  const int fch = (tid & 1) * 16;

  const int kbeg = (MODE == 3) ? blockIdx.y * 1024 : 0;
  const int kend = (MODE == 3) ? kbeg + 1024 : K;

  f32x4 arf[4], brf[4];
  bf16x8 arb[2], brb[2];

  auto load_regs = [&](int k0) {
    if constexpr (A_F32) {
      const float* src = (const float*)Ap + (size_t)(tm + frow) * K + k0 + fch;
      arf[0] = *(const f32x4*)(src);
      arf[1] = *(const f32x4*)(src + 4);
      arf[2] = *(const f32x4*)(src + 8);
      arf[3] = *(const f32x4*)(src + 12);
    } else {
      const bf16* Ab = (const bf16*)Ap;
#pragma unroll
      for (int pc = 0; pc < 2; ++pc) {
        const int c = tid + pc * 256;
        const int r = c >> 2, col = (c & 3) * 8;
        arb[pc] = *(const bf16x8*)(Ab + (size_t)(tm + r) * K + k0 + col);
      }
    }
    if constexpr (B_F32) {
      const float* src = (const float*)Bp + (size_t)(tn + frow) * K + k0 + fch;
      brf[0] = *(const f32x4*)(src);
      brf[1] = *(const f32x4*)(src + 4);
      brf[2] = *(const f32x4*)(src + 8);
      brf[3] = *(const f32x4*)(src + 12);
    } else {
      const bf16* Bb = (const bf16*)Bp;
#pragma unroll
      for (int pc = 0; pc < 2; ++pc) {
        const int c = tid + pc * 256;
        const int r = c >> 2, col = (c & 3) * 8;
        brb[pc] = *(const bf16x8*)(Bb + (size_t)(tn + r) * K + k0 + col);
      }
    }
  };
  auto write_lds = [&]() {
    if constexpr (A_F32) {
      bf16x8 y0, y1;
#pragma unroll
      for (int j = 0; j < 4; ++j) {
        y0[j] = (bf16)arf[0][j]; y0[j + 4] = (bf16)arf[1][j];
        y1[j] = (bf16)arf[2][j]; y1[j + 4] = (bf16)arf[3][j];
      }
      *(bf16x8*)(As + frow * SLD + fch) = y0;
      *(bf16x8*)(As + frow * SLD + fch + 8) = y1;
    } else {
#pragma unroll
      for (int pc = 0; pc < 2; ++pc) {
        const int c = tid + pc * 256;
        const int r = c >> 2, col = (c & 3) * 8;
        *(bf16x8*)(As + r * SLD + col) = arb[pc];
      }
    }
    if constexpr (B_F32) {
      bf16x8 y0, y1;
#pragma unroll
      for (int j = 0; j < 4; ++j) {
        y0[j] = (bf16)brf[0][j]; y0[j + 4] = (bf16)brf[1][j];
        y1[j] = (bf16)brf[2][j]; y1[j + 4] = (bf16)brf[3][j];
      }
      *(bf16x8*)(Bs + frow * SLD + fch) = y0;
      *(bf16x8*)(Bs + frow * SLD + fch + 8) = y1;
    } else {
#pragma unroll
      for (int pc = 0; pc < 2; ++pc) {
        const int c = tid + pc * 256;
        const int r = c >> 2, col = (c & 3) * 8;
        *(bf16x8*)(Bs + r * SLD + col) = brb[pc];
      }
    }
  };

  load_regs(kbeg);
  write_lds();
  __syncthreads();

  for (int k0 = kbeg; k0 < kend; k0 += 32) {
    const bool more = (k0 + 32) < kend;
    if (more) load_regs(k0 + 32);

    bf16x8 af[4], bfr[4];
#pragma unroll
    for (int i = 0; i < 4; ++i)
      af[i] = *(const bf16x8*)(As + (wm + i * 16 + l15) * SLD + quad * 8);
#pragma unroll
    for (int j = 0; j < 4; ++j)
      bfr[j] = *(const bf16x8*)(Bs + (wn + j * 16 + l15) * SLD + quad * 8);
#pragma unroll
    for (int i = 0; i < 4; ++i)
#pragma unroll
      for (int j = 0; j < 4; ++j)
        acc[i][j] = __builtin_amdgcn_mfma_f32_16x16x32_bf16(af[i], bfr[j], acc[i][j], 0, 0, 0);

    __syncthreads();
    if (more) {
      write_lds();
      __syncthreads();
    }
  }

  const size_t koff = (MODE == 3) ? (size_t)blockIdx.y * M * N : 0;
#pragma unroll
  for (int i = 0; i < 4; ++i) {
#pragma unroll
    for (int j = 0; j < 4; ++j) {
      const int n = tn + wn + j * 16 + l15;
      const float bv = (MODE == 3) ? 0.f : bias[n];
#pragma unroll
      for (int r = 0; r < 4; ++r) {
        const int m = tm + wm + i * 16 + quad * 4 + r;
        const float v = (MODE == 3) ? acc[i][j][r] : (acc[i][j][r] + bv) * oscale;
        C[koff + (size_t)m * N + n] = (CT)v;
      }
    }
  }
}

// Sum 8 split-K partials + bias -> f32 out. 1024x1024 elements, f32x4.
__global__ __launch_bounds__(256)
void splitk_reduce(const float* __restrict__ P, const float* __restrict__ bias,
                   float* __restrict__ out) {
  const int i = (blockIdx.x * 256 + threadIdx.x) * 4;
  const int n = i & 1023;
  f32x4 s = *(const f32x4*)(bias + n);
#pragma unroll
  for (int kc = 0; kc < 8; ++kc)
    s += *(const f32x4*)(P + (size_t)kc * 1048576 + i);
  *(f32x4*)(out + i) = s;
}

// ---------------------------------------------------------------------------
// Flash attention, 32x32 swapped-operand structure (learn_hip m214 ladder).
// Q: [bh][2048][128] bf16 (pre-scaled by log2e/32), K: [bh][2048][128] in
// permuted key order k'', V^T: [bh][128][2048] same order. Key order is
// irrelevant to the math (softmax is permutation-invariant); Q/O stay in
// canonical t order. T5: setprio(1) around both MFMA clusters.
// ---------------------------------------------------------------------------
__global__ __launch_bounds__(256, 2)
void attn_kernel(const bf16* __restrict__ Q, const bf16* __restrict__ Kc,
                 const bf16* __restrict__ Vt, bf16* __restrict__ O2) {
  __shared__ bf16x8 KsV[1024];  // 64 keys x 128 d  (16KB)
  __shared__ bf16x8 VsV[1024];  // 128 d  x 64 keys (16KB)
  char* KsB = (char*)KsV;
  char* VsB = (char*)VsV;

  const int tid = threadIdx.x;
  const int w = tid >> 6, l = tid & 63;
  const int l31 = l & 31, hi = l >> 5;
  // XCD-chunked swizzle: 64 consecutive wg per XCD = 4 full (b,h) groups.
  const int wg = ((blockIdx.x & 7) << 6) | (blockIdx.x >> 3);
  const int bh = wg >> 4;
  const int qc = wg & 15;
  const int b = bh >> 3, h = bh & 7;
  const int q0w = qc * 128 + w * 32;
  const size_t qkbase = (size_t)bh * 2048 * 128;
  const size_t vbase = (size_t)bh * 128 * 2048;

  bf16x8 qf[8];
#pragma unroll
  for (int dc = 0; dc < 8; ++dc)
    qf[dc] = *(const bf16x8*)(Q + qkbase + (size_t)(q0w + l31) * 128 + dc * 16 + hi * 8);

  f32x16 oacc[4] = {};
  float m = -1e30f, lsum = 0.f;

  bf16x8 kreg[4], vreg[4];
  auto stage_load = [&](int kk) {
#pragma unroll
    for (int pc = 0; pc < 4; ++pc) {
      const int c = tid + pc * 256;
      kreg[pc] = *(const bf16x8*)(Kc + qkbase + (size_t)(kk + (c >> 4)) * 128 + (c & 15) * 8);
      vreg[pc] = *(const bf16x8*)(Vt + vbase + (size_t)(c >> 3) * 2048 + kk + (c & 7) * 8);
    }
  };
  auto stage_write = [&]() {
#pragma unroll
    for (int pc = 0; pc < 4; ++pc) {
      const int c = tid + pc * 256;
      const int kr = c >> 4, kcol = c & 15;
      *(bf16x8*)(KsB + ((kr * 256 + kcol * 16) ^ ((kr & 15) << 4))) = kreg[pc];
      const int vr = c >> 3, vcol = c & 7;
      *(bf16x8*)(VsB + ((vr * 128 + vcol * 16) ^ ((vr & 7) << 4))) = vreg[pc];
    }
  };

  stage_load(0);
  stage_write();
  __syncthreads();

  for (int it = 0; it < 32; ++it) {
    if (it < 31) stage_load((it + 1) * 64);

    f32x16 sa = {}, sb = {};
    __builtin_amdgcn_s_setprio(1);
#pragma unroll
    for (int dc = 0; dc < 8; ++dc) {
      const int colb = dc * 32 + hi * 16;
      bf16x8 ka = *(const bf16x8*)(KsB + ((l31 * 256 + colb) ^ ((l31 & 15) << 4)));
      bf16x8 kb = *(const bf16x8*)(KsB + (((32 + l31) * 256 + colb) ^ ((l31 & 15) << 4)));
      sa = __builtin_amdgcn_mfma_f32_32x32x16_bf16(ka, qf[dc], sa, 0, 0, 0);
      sb = __builtin_amdgcn_mfma_f32_32x32x16_bf16(kb, qf[dc], sb, 0, 0, 0);
    }
    __builtin_amdgcn_s_setprio(0);

    float mt;
    {
      float a0 = fmaxf(fmaxf(sa[0], sa[1]), fmaxf(sa[2], sa[3]));
      float a1 = fmaxf(fmaxf(sa[4], sa[5]), fmaxf(sa[6], sa[7]));
      float a2 = fmaxf(fmaxf(sa[8], sa[9]), fmaxf(sa[10], sa[11]));
      float a3 = fmaxf(fmaxf(sa[12], sa[13]), fmaxf(sa[14], sa[15]));
      float b0 = fmaxf(fmaxf(sb[0], sb[1]), fmaxf(sb[2], sb[3]));
      float b1 = fmaxf(fmaxf(sb[4], sb[5]), fmaxf(sb[6], sb[7]));
      float b2 = fmaxf(fmaxf(sb[8], sb[9]), fmaxf(sb[10], sb[11]));
      float b3 = fmaxf(fmaxf(sb[12], sb[13]), fmaxf(sb[14], sb[15]));
      mt = fmaxf(fmaxf(fmaxf(a0, a1), fmaxf(a2, a3)),
                 fmaxf(fmaxf(b0, b1), fmaxf(b2, b3)));
      mt = xhalf_max(mt);
    }
    if (!__all(mt - m <= 8.0f)) {
      const float mn = fmaxf(m, mt);
      const float al = __builtin_amdgcn_exp2f(m - mn);
      m = mn;
      lsum *= al;
#pragma unroll
      for (int dt = 0; dt < 4; ++dt)
#pragma unroll
        for (int i = 0; i < 16; ++i) oacc[dt][i] *= al;
    }
#pragma unroll
    for (int i = 0; i < 16; ++i) sa[i] = __builtin_amdgcn_exp2f(sa[i] - m);
#pragma unroll
    for (int i = 0; i < 16; ++i) sb[i] = __builtin_amdgcn_exp2f(sb[i] - m);
    float r0 = 0.f, r1 = 0.f, r2 = 0.f, r3 = 0.f;
#pragma unroll
    for (int i = 0; i < 4; ++i) {
      r0 += sa[i]; r1 += sa[4 + i]; r2 += sa[8 + i]; r3 += sa[12 + i];
    }
#pragma unroll
    for (int i = 0; i < 4; ++i) {
      r0 += sb[i]; r1 += sb[4 + i]; r2 += sb[8 + i]; r3 += sb[12 + i];
    }
    lsum += xhalf_sum((r0 + r1) + (r2 + r3));

    bf16x8 pf[4];
    pf[0] = build_pfrag<0>(sa);
    pf[1] = build_pfrag<2>(sa);
    pf[2] = build_pfrag<0>(sb);
    pf[3] = build_pfrag<2>(sb);

    __builtin_amdgcn_s_setprio(1);
#pragma unroll
    for (int dt = 0; dt < 4; ++dt) {
      const int d = dt * 32 + l31;
#pragma unroll
      for (int c = 0; c < 4; ++c) {
        bf16x8 vf = *(const bf16x8*)(VsB + ((d * 128 + c * 32 + hi * 16) ^ ((d & 7) << 4)));
        oacc[dt] = __builtin_amdgcn_mfma_f32_32x32x16_bf16(vf, pf[c], oacc[dt], 0, 0, 0);
      }
    }
    __builtin_amdgcn_s_setprio(0);

    __syncthreads();
    if (it < 31) stage_write();
    __syncthreads();
  }

  const float inv = 1.0f / lsum;
  const int t = q0w + l31;
  const size_t obase = (size_t)(b * 256 + (t >> 3)) * 8192 + (t & 7) * 1024 + h * 128;
#pragma unroll
  for (int dt = 0; dt < 4; ++dt) {
#pragma unroll
    for (int g = 0; g < 4; ++g) {
      const int d = dt * 32 + 8 * g + 4 * hi;
      bf16x4 ov;
#pragma unroll
      for (int r = 0; r < 4; ++r) ov[r] = (bf16)(oacc[dt][g * 4 + r] * inv);
      *(bf16x4*)(O2 + obase + d) = ov;
    }
  }
}

extern "C" void kernel_launch(void* const* d_in, const int* in_sizes, int n_in,
                              void* d_out, int out_size, void* d_ws, size_t ws_size,
                              hipStream_t stream) {
  const float* query = (const float*)d_in[0];
  const float* key_ = (const float*)d_in[1];
  const float* value = (const float*)d_in[2];
  const float* Wq = (const float*)d_in[3];
  const float* bq = (const float*)d_in[4];
  const float* Wk = (const float*)d_in[5];
  const float* bk = (const float*)d_in[6];
  const float* Wv = (const float*)d_in[7];
  const float* bv = (const float*)d_in[8];
  const float* Wfc = (const float*)d_in[9];
  const float* bfc = (const float*)d_in[10];
  float* out = (float*)d_out;  // output dtype is FLOAT32 (verified round 7)

  const size_t T8M = (size_t)8 * 1024 * 1024;  // 8M bf16 = 16MB per region
  bf16* Qws = (bf16*)d_ws;
  bf16* Kws = Qws + T8M;
  bf16* Vtw = Kws + T8M;
  bf16* O2 = Vtw + T8M;  // 64MB total (ws_size >= 64MB verified round 5)
  // split-K partials (8 x 1024x1024 f32 = 32MB) reuse Q/K regions (dead
  // after attn_kernel).
  float* Pk = (float*)d_ws;

  // Fold 1/sqrt(HID) and log2(e) into Q: attention softmax in exp2 domain.
  const float QSC = 1.4426950408889634f / 32.0f;

  dim3 blk(256);
  // fused QKV projections: one dispatch, 1536 blocks (3 slices x 512)
  qkv_proj<<<dim3(512, 3), blk, 0, stream>>>(query, key_, value, Wq, Wk, Wv,
                                             bq, bk, bv, Qws, Kws, Vtw, QSC);
  // attention: 32 (b,h) x 16 q-chunks of 128 rows
  attn_kernel<<<512, blk, 0, stream>>>(Qws, Kws, Vtw, O2);
  // output projection, split-K x8
  gemm_nt<3, false, true, float><<<dim3(64, 8), blk, 0, stream>>>(O2, Wfc, nullptr, Pk, 1024, 1024, 8192, 1.0f);
  splitk_reduce<<<1024, blk, 0, stream>>>(Pk, bfc, out);
}

// Round 3
// 363.287 us; speedup vs baseline: 1.2795x; 1.2795x over previous
//
#include <hip/hip_runtime.h>
#include <cstdint>
#include <cstddef>

typedef __bf16 bf16;
typedef __bf16 bf16x4 __attribute__((ext_vector_type(4)));
typedef __bf16 bf16x8 __attribute__((ext_vector_type(8)));
typedef float f32x4 __attribute__((ext_vector_type(4)));
typedef float f32x16 __attribute__((ext_vector_type(16)));
typedef unsigned int uint2v __attribute__((ext_vector_type(2)));

#define SLD 40  // fallback GEMM LDS row stride (elements)

// ---------------------------------------------------------------------------
// permlane32_swap helpers (attn softmax cross-half exchange)
// ---------------------------------------------------------------------------
__device__ __forceinline__ void plswap(unsigned& a, unsigned& b) {
  uint2v r = __builtin_amdgcn_permlane32_swap(a, b, false, false);
  a = r[0];
  b = r[1];
}
__device__ __forceinline__ float xhalf_max(float x) {
  unsigned a = __float_as_uint(x), b = a;
  plswap(a, b);
  return fmaxf(__uint_as_float(a), __uint_as_float(b));
}
__device__ __forceinline__ float xhalf_sum(float x) {
  unsigned a = __float_as_uint(x), b = a;
  plswap(a, b);
  return __uint_as_float(a) + __uint_as_float(b);
}
__device__ __forceinline__ unsigned cvtpk(float lo, float hi) {
  unsigned r;
  asm("v_cvt_pk_bf16_f32 %0, %1, %2" : "=v"(r) : "v"(lo), "v"(hi));
  return r;
}

template <int G0>
__device__ __forceinline__ bf16x8 build_pfrag(const f32x16& X) {
  unsigned a0 = cvtpk(X[G0 * 4 + 0], X[G0 * 4 + 1]);
  unsigned b0 = cvtpk(X[G0 * 4 + 4], X[G0 * 4 + 5]);
  plswap(a0, b0);
  unsigned a1 = cvtpk(X[G0 * 4 + 2], X[G0 * 4 + 3]);
  unsigned b1 = cvtpk(X[G0 * 4 + 6], X[G0 * 4 + 7]);
  plswap(a1, b1);
  union {
    unsigned w[4];
    bf16x8 v;
  } u;
  u.w[0] = a0;
  u.w[1] = a1;
  u.w[2] = b0;
  u.w[3] = b1;
  return u.v;
}

// ---------------------------------------------------------------------------
// FAST PATH (ws_size >= 120MB): f32->bf16 convert pass + global_load_lds GEMMs
// (m97 structure: 128x128 tile, BK=32, linear LDS, DMA staging, 2 barriers).
// ---------------------------------------------------------------------------
__device__ __forceinline__ void gload16(const bf16* g, bf16* l) {
  __builtin_amdgcn_global_load_lds(
      (const __attribute__((address_space(1))) void*)g,
      (__attribute__((address_space(3))) void*)l, 16, 0, 0);
}

// Convert 3x X (1M f32) + 3x W (8M f32) to bf16. Grid (4096, 6).
__global__ __launch_bounds__(256)
void cvt6(const float* __restrict__ x0, const float* __restrict__ x1,
          const float* __restrict__ x2, const float* __restrict__ w0,
          const float* __restrict__ w1, const float* __restrict__ w2,
          bf16* __restrict__ xo, bf16* __restrict__ wo) {
  const int y = blockIdx.y;
  const float* s;
  bf16* d;
  int n;
  if (y < 3) {
    s = (y == 0) ? x0 : (y == 1) ? x1 : x2;
    d = xo + (size_t)y * 1048576;
    n = 1048576;
  } else {
    const int z = y - 3;
    s = (z == 0) ? w0 : (z == 1) ? w1 : w2;
    d = wo + (size_t)z * 8388608;
    n = 8388608;
  }
  const int i = (blockIdx.x * 256 + threadIdx.x) * 8;
  if (i >= n) return;
  f32x4 a = *(const f32x4*)(s + i);
  f32x4 b = *(const f32x4*)(s + i + 4);
  bf16x8 v;
#pragma unroll
  for (int j = 0; j < 4; ++j) {
    v[j] = (bf16)a[j];
    v[j + 4] = (bf16)b[j];
  }
  *(bf16x8*)(d + i) = v;
}

__global__ __launch_bounds__(256)
void cvt1(const float* __restrict__ s, bf16* __restrict__ d, int n) {
  const int i = (blockIdx.x * 256 + threadIdx.x) * 8;
  if (i >= n) return;
  f32x4 a = *(const f32x4*)(s + i);
  f32x4 b = *(const f32x4*)(s + i + 4);
  bf16x8 v;
#pragma unroll
  for (int j = 0; j < 4; ++j) {
    v[j] = (bf16)a[j];
    v[j + 4] = (bf16)b[j];
  }
  *(bf16x8*)(d + i) = v;
}

// Shared K-loop: NT GEMM 128x128 tile, BK=32, global_load_lds staging into
// LINEAR LDS [128][32] (padding would break the DMA's lane->LDS mapping).
// Chunk c (of 8) = rows 16c..16c+15; lane i covers row 16c+(i>>2), col (i&3)*8.
__device__ __forceinline__ void gemm_core(const bf16* __restrict__ A,
                                          const bf16* __restrict__ B,
                                          bf16* As, bf16* Bs, int K, int kbeg,
                                          int kend, int tm, int tn,
                                          f32x4 (&acc)[4][4]) {
  const int tid = threadIdx.x;
  const int w = tid >> 6, l = tid & 63;
  const int l15 = l & 15, quad = l >> 4;
  const int wm = (w >> 1) << 6, wn = (w & 1) << 6;
  const int rsub = l >> 2, csub = (l & 3) * 8;

  for (int k0 = kbeg; k0 < kend; k0 += 32) {
#pragma unroll
    for (int c2 = 0; c2 < 2; ++c2) {
      const int c = w * 2 + c2;
      gload16(A + (size_t)(tm + c * 16 + rsub) * K + k0 + csub, As + c * 512);
      gload16(B + (size_t)(tn + c * 16 + rsub) * K + k0 + csub, Bs + c * 512);
    }
    __syncthreads();  // compiler drains vmcnt(0) here (DMA -> LDS visible)
    bf16x8 af[4], bfr[4];
#pragma unroll
    for (int i = 0; i < 4; ++i)
      af[i] = *(const bf16x8*)(As + (wm + i * 16 + l15) * 32 + quad * 8);
#pragma unroll
    for (int j = 0; j < 4; ++j)
      bfr[j] = *(const bf16x8*)(Bs + (wn + j * 16 + l15) * 32 + quad * 8);
#pragma unroll
    for (int i = 0; i < 4; ++i)
#pragma unroll
      for (int j = 0; j < 4; ++j)
        acc[i][j] = __builtin_amdgcn_mfma_f32_16x16x32_bf16(af[i], bfr[j],
                                                            acc[i][j], 0, 0, 0);
    __syncthreads();  // protect LDS before next iteration's DMA
  }
}

// Fused QKV projection, bf16 inputs. Grid (512, 3); blockIdx.y = slice.
// Scatter layouts (identical to fallback path):
//   slice 0 (Q): [bh][t][d],   t  = s*8 + c   (osc = qsc)
//   slice 1 (K): [bh][k''][d], k'' = c*256+s  (permuted key order)
//   slice 2 (V): [bh][d][k'']  (V^T, permuted) -> bf16x4 vectorized stores
__global__ __launch_bounds__(256)
void qkv_gemm_lds(const bf16* __restrict__ Xc, const bf16* __restrict__ Wc,
                  const float* __restrict__ Bq, const float* __restrict__ Bk,
                  const float* __restrict__ Bv, bf16* __restrict__ Qo,
                  bf16* __restrict__ Ko, bf16* __restrict__ Vo, float qsc) {
  __shared__ bf16 As[128 * 32];
  __shared__ bf16 Bs[128 * 32];
  const int slice = blockIdx.y;
  const bf16* A = Xc + (size_t)slice * 1048576;
  const bf16* B = Wc + (size_t)slice * 8388608;
  const float* bias = (slice == 0) ? Bq : (slice == 1) ? Bk : Bv;
  const int tm = (blockIdx.x >> 6) << 7;  // tiles_n = 64
  const int tn = (blockIdx.x & 63) << 7;

  f32x4 acc[4][4] = {};
  gemm_core(A, B, As, Bs, 1024, 0, 1024, tm, tn, acc);

  const int tid = threadIdx.x;
  const int w = tid >> 6, l = tid & 63;
  const int l15 = l & 15, quad = l >> 4;
  const int wm = (w >> 1) << 6, wn = (w & 1) << 6;

  if (slice == 2) {
#pragma unroll
    for (int i = 0; i < 4; ++i) {
#pragma unroll
      for (int j = 0; j < 4; ++j) {
        const int n = tn + wn + j * 16 + l15;
        const int d = n & 127, h = (n >> 7) & 7, c = n >> 10;
        const float bv = bias[n];
        const int m0 = tm + wm + i * 16 + quad * 4;
        const int b = m0 >> 8, s0 = m0 & 255;
        const size_t idx = ((size_t)((b * 8 + h) * 128 + d)) * 2048 + (c << 8) + s0;
        bf16x4 ov;
#pragma unroll
        for (int r = 0; r < 4; ++r) ov[r] = (bf16)(acc[i][j][r] + bv);
        *(bf16x4*)(Vo + idx) = ov;
      }
    }
  } else {
    bf16* O = slice ? Ko : Qo;
    const float osc = slice ? 1.0f : qsc;
#pragma unroll
    for (int i = 0; i < 4; ++i) {
#pragma unroll
      for (int j = 0; j < 4; ++j) {
        const int n = tn + wn + j * 16 + l15;
        const int d = n & 127, h = (n >> 7) & 7, c = n >> 10;
        const float bv = bias[n];
#pragma unroll
        for (int r = 0; r < 4; ++r) {
          const int m = tm + wm + i * 16 + quad * 4 + r;
          const int b = m >> 8, s = m & 255;
          const int row = slice ? ((c << 8) | s) : ((s << 3) | c);
          const size_t idx = ((size_t)(b * 8 + h) * 2048 + row) * 128 + d;
          O[idx] = (bf16)((acc[i][j][r] + bv) * osc);
        }
      }
    }
  }
}

// Output projection, split-K x8: A=O2[1024][8192], B=Wfcc[1024][8192] bf16.
// Grid (64, 8): x = 8x8 tiles of 128, y = K-slice of 1024. f32 partials.
__global__ __launch_bounds__(256)
void fc_gemm_lds(const bf16* __restrict__ A, const bf16* __restrict__ B,
                 float* __restrict__ C) {
  __shared__ bf16 As[128 * 32];
  __shared__ bf16 Bs[128 * 32];
  const int tm = (blockIdx.x >> 3) << 7;
  const int tn = (blockIdx.x & 7) << 7;
  const int kbeg = blockIdx.y << 10;

  f32x4 acc[4][4] = {};
  gemm_core(A, B, As, Bs, 8192, kbeg, kbeg + 1024, tm, tn, acc);

  const int tid = threadIdx.x;
  const int w = tid >> 6, l = tid & 63;
  const int l15 = l & 15, quad = l >> 4;
  const int wm = (w >> 1) << 6, wn = (w & 1) << 6;
  const size_t koff = (size_t)blockIdx.y * 1048576;
#pragma unroll
  for (int i = 0; i < 4; ++i) {
#pragma unroll
    for (int j = 0; j < 4; ++j) {
      const int n = tn + wn + j * 16 + l15;
#pragma unroll
      for (int r = 0; r < 4; ++r) {
        const int m = tm + wm + i * 16 + quad * 4 + r;
        C[koff + (size_t)m * 1024 + n] = acc[i][j][r];
      }
    }
  }
}

// ---------------------------------------------------------------------------
// FALLBACK PATH (ws_size < 120MB): round-2 kernels, verified within 64MB ws.
// ---------------------------------------------------------------------------
__global__ __launch_bounds__(256, 4)
void qkv_proj(const float* __restrict__ Xq, const float* __restrict__ Xk,
              const float* __restrict__ Xv, const float* __restrict__ Wq,
              const float* __restrict__ Wk, const float* __restrict__ Wv,
              const float* __restrict__ Bq, const float* __restrict__ Bk,
              const float* __restrict__ Bv, bf16* __restrict__ Qo,
              bf16* __restrict__ Ko, bf16* __restrict__ Vo, float qsc) {
  __shared__ bf16 As[128 * SLD];
  __shared__ bf16 Bs[128 * SLD];
  const int slice = blockIdx.y;
  const float* A = (slice == 0) ? Xq : (slice == 1) ? Xk : Xv;
  const float* W = (slice == 0) ? Wq : (slice == 1) ? Wk : Wv;
  const float* bias = (slice == 0) ? Bq : (slice == 1) ? Bk : Bv;

  const int tid = threadIdx.x;
  const int w = tid >> 6, l = tid & 63;
  const int l15 = l & 15, quad = l >> 4;
  const int tm = (blockIdx.x >> 6) << 7;
  const int tn = (blockIdx.x & 63) << 7;
  const int wm = (w >> 1) << 6;
  const int wn = (w & 1) << 6;

  const int frow = tid >> 1;
  const int fch = (tid & 1) * 16;

  f32x4 acc[4][4] = {};
  f32x4 ar[4], br[4];

  auto load_regs = [&](int k0) {
    const float* sA = A + (size_t)(tm + frow) * 1024 + k0 + fch;
    ar[0] = *(const f32x4*)(sA);
    ar[1] = *(const f32x4*)(sA + 4);
    ar[2] = *(const f32x4*)(sA + 8);
    ar[3] = *(const f32x4*)(sA + 12);
    const float* sB = W + (size_t)(tn + frow) * 1024 + k0 + fch;
    br[0] = *(const f32x4*)(sB);
    br[1] = *(const f32x4*)(sB + 4);
    br[2] = *(const f32x4*)(sB + 8);
    br[3] = *(const f32x4*)(sB + 12);
  };
  auto write_lds = [&]() {
    bf16x8 y0, y1;
#pragma unroll
    for (int j = 0; j < 4; ++j) {
      y0[j] = (bf16)ar[0][j]; y0[j + 4] = (bf16)ar[1][j];
      y1[j] = (bf16)ar[2][j]; y1[j + 4] = (bf16)ar[3][j];
    }
    *(bf16x8*)(As + frow * SLD + fch) = y0;
    *(bf16x8*)(As + frow * SLD + fch + 8) = y1;
#pragma unroll
    for (int j = 0; j < 4; ++j) {
      y0[j] = (bf16)br[0][j]; y0[j + 4] = (bf16)br[1][j];
      y1[j] = (bf16)br[2][j]; y1[j + 4] = (bf16)br[3][j];
    }
    *(bf16x8*)(Bs + frow * SLD + fch) = y0;
    *(bf16x8*)(Bs + frow * SLD + fch + 8) = y1;
  };

  load_regs(0);
  write_lds();
  __syncthreads();

  for (int k0 = 0; k0 < 1024; k0 += 32) {
    const bool more = (k0 + 32) < 1024;
    if (more) load_regs(k0 + 32);

    bf16x8 af[4], bfr[4];
#pragma unroll
    for (int i = 0; i < 4; ++i)
      af[i] = *(const bf16x8*)(As + (wm + i * 16 + l15) * SLD + quad * 8);
#pragma unroll
    for (int j = 0; j < 4; ++j)
      bfr[j] = *(const bf16x8*)(Bs + (wn + j * 16 + l15) * SLD + quad * 8);
#pragma unroll
    for (int i = 0; i < 4; ++i)
#pragma unroll
      for (int j = 0; j < 4; ++j)
        acc[i][j] = __builtin_amdgcn_mfma_f32_16x16x32_bf16(af[i], bfr[j], acc[i][j], 0, 0, 0);

    __syncthreads();
    if (more) {
      write_lds();
      __syncthreads();
    }
  }

  if (slice == 2) {
#pragma unroll
    for (int i = 0; i < 4; ++i) {
#pragma unroll
      for (int j = 0; j < 4; ++j) {
        const int n = tn + wn + j * 16 + l15;
        const int d = n & 127, h = (n >> 7) & 7, c = n >> 10;
        const float bv = bias[n];
        const int m0 = tm + wm + i * 16 + quad * 4;
        const int b = m0 >> 8, s0 = m0 & 255;
        const size_t idx = ((size_t)((b * 8 + h) * 128 + d)) * 2048 + (c << 8) + s0;
        bf16x4 ov;
#pragma unroll
        for (int r = 0; r < 4; ++r) ov[r] = (bf16)(acc[i][j][r] + bv);
        *(bf16x4*)(Vo + idx) = ov;
      }
    }
  } else {
    bf16* O = slice ? Ko : Qo;
    const float osc = slice ? 1.0f : qsc;
#pragma unroll
    for (int i = 0; i < 4; ++i) {
#pragma unroll
      for (int j = 0; j < 4; ++j) {
        const int n = tn + wn + j * 16 + l15;
        const int d = n & 127, h = (n >> 7) & 7, c = n >> 10;
        const float bv = bias[n];
#pragma unroll
        for (int r = 0; r < 4; ++r) {
          const int m = tm + wm + i * 16 + quad * 4 + r;
          const int b = m >> 8, s = m & 255;
          const int row = slice ? ((c << 8) | s) : ((s << 3) | c);
          const size_t idx = ((size_t)(b * 8 + h) * 2048 + row) * 128 + d;
          O[idx] = (bf16)((acc[i][j][r] + bv) * osc);
        }
      }
    }
  }
}

// Fallback output projection (B f32), split-K partials.
__global__ __launch_bounds__(256, 4)
void gemm_fc_f32(const bf16* __restrict__ Ap, const float* __restrict__ Bp,
                 float* __restrict__ C) {
  __shared__ bf16 As[128 * SLD];
  __shared__ bf16 Bs[128 * SLD];
  const int tid = threadIdx.x;
  const int w = tid >> 6, l = tid & 63;
  const int l15 = l & 15, quad = l >> 4;
  const int tm = (blockIdx.x >> 3) << 7;
  const int tn = (blockIdx.x & 7) << 7;
  const int wm = (w >> 1) << 6;
  const int wn = (w & 1) << 6;
  const int K = 8192;

  f32x4 acc[4][4] = {};
  const int frow = tid >> 1;
  const int fch = (tid & 1) * 16;
  const int kbeg = blockIdx.y << 10;
  const int kend = kbeg + 1024;

  f32x4 brf[4];
  bf16x8 arb[2];

  auto load_regs = [&](int k0) {
#pragma unroll
    for (int pc = 0; pc < 2; ++pc) {
      const int c = tid + pc * 256;
      const int r = c >> 2, col = (c & 3) * 8;
      arb[pc] = *(const bf16x8*)(Ap + (size_t)(tm + r) * K + k0 + col);
    }
    const float* src = Bp + (size_t)(tn + frow) * K + k0 + fch;
    brf[0] = *(const f32x4*)(src);
    brf[1] = *(const f32x4*)(src + 4);
    brf[2] = *(const f32x4*)(src + 8);
    brf[3] = *(const f32x4*)(src + 12);
  };
  auto write_lds = [&]() {
#pragma unroll
    for (int pc = 0; pc < 2; ++pc) {
      const int c = tid + pc * 256;
      const int r = c >> 2, col = (c & 3) * 8;
      *(bf16x8*)(As + r * SLD + col) = arb[pc];
    }
    bf16x8 y0, y1;
#pragma unroll
    for (int j = 0; j < 4; ++j) {
      y0[j] = (bf16)brf[0][j]; y0[j + 4] = (bf16)brf[1][j];
      y1[j] = (bf16)brf[2][j]; y1[j + 4] = (bf16)brf[3][j];
    }
    *(bf16x8*)(Bs + frow * SLD + fch) = y0;
    *(bf16x8*)(Bs + frow * SLD + fch + 8) = y1;
  };

  load_regs(kbeg);
  write_lds();
  __syncthreads();

  for (int k0 = kbeg; k0 < kend; k0 += 32) {
    const bool more = (k0 + 32) < kend;
    if (more) load_regs(k0 + 32);

    bf16x8 af[4], bfr[4];
#pragma unroll
    for (int i = 0; i < 4; ++i)
      af[i] = *(const bf16x8*)(As + (wm + i * 16 + l15) * SLD + quad * 8);
#pragma unroll
    for (int j = 0; j < 4; ++j)
      bfr[j] = *(const bf16x8*)(Bs + (wn + j * 16 + l15) * SLD + quad * 8);
#pragma unroll
    for (int i = 0; i < 4; ++i)
#pragma unroll
      for (int j = 0; j < 4; ++j)
        acc[i][j] = __builtin_amdgcn_mfma_f32_16x16x32_bf16(af[i], bfr[j], acc[i][j], 0, 0, 0);

    __syncthreads();
    if (more) {
      write_lds();
      __syncthreads();
    }
  }

  const size_t koff = (size_t)blockIdx.y * 1048576;
#pragma unroll
  for (int i = 0; i < 4; ++i) {
#pragma unroll
    for (int j = 0; j < 4; ++j) {
      const int n = tn + wn + j * 16 + l15;
#pragma unroll
      for (int r = 0; r < 4; ++r) {
        const int m = tm + wm + i * 16 + quad * 4 + r;
        C[koff + (size_t)m * 1024 + n] = acc[i][j][r];
      }
    }
  }
}

// Sum 8 split-K partials + bias -> f32 out. (shared by both paths)
__global__ __launch_bounds__(256)
void splitk_reduce(const float* __restrict__ P, const float* __restrict__ bias,
                   float* __restrict__ out) {
  const int i = (blockIdx.x * 256 + threadIdx.x) * 4;
  const int n = i & 1023;
  f32x4 s = *(const f32x4*)(bias + n);
#pragma unroll
  for (int kc = 0; kc < 8; ++kc)
    s += *(const f32x4*)(P + (size_t)kc * 1048576 + i);
  *(f32x4*)(out + i) = s;
}

// ---------------------------------------------------------------------------
// Flash attention, 32x32 swapped-operand structure (shared by both paths).
// ---------------------------------------------------------------------------
__global__ __launch_bounds__(256, 2)
void attn_kernel(const bf16* __restrict__ Q, const bf16* __restrict__ Kc,
                 const bf16* __restrict__ Vt, bf16* __restrict__ O2) {
  __shared__ bf16x8 KsV[1024];  // 64 keys x 128 d  (16KB)
  __shared__ bf16x8 VsV[1024];  // 128 d  x 64 keys (16KB)
  char* KsB = (char*)KsV;
  char* VsB = (char*)VsV;

  const int tid = threadIdx.x;
  const int w = tid >> 6, l = tid & 63;
  const int l31 = l & 31, hi = l >> 5;
  const int wg = ((blockIdx.x & 7) << 6) | (blockIdx.x >> 3);
  const int bh = wg >> 4;
  const int qc = wg & 15;
  const int b = bh >> 3, h = bh & 7;
  const int q0w = qc * 128 + w * 32;
  const size_t qkbase = (size_t)bh * 2048 * 128;
  const size_t vbase = (size_t)bh * 128 * 2048;

  bf16x8 qf[8];
#pragma unroll
  for (int dc = 0; dc < 8; ++dc)
    qf[dc] = *(const bf16x8*)(Q + qkbase + (size_t)(q0w + l31) * 128 + dc * 16 + hi * 8);

  f32x16 oacc[4] = {};
  float m = -1e30f, lsum = 0.f;

  bf16x8 kreg[4], vreg[4];
  auto stage_load = [&](int kk) {
#pragma unroll
    for (int pc = 0; pc < 4; ++pc) {
      const int c = tid + pc * 256;
      kreg[pc] = *(const bf16x8*)(Kc + qkbase + (size_t)(kk + (c >> 4)) * 128 + (c & 15) * 8);
      vreg[pc] = *(const bf16x8*)(Vt + vbase + (size_t)(c >> 3) * 2048 + kk + (c & 7) * 8);
    }
  };
  auto stage_write = [&]() {
#pragma unroll
    for (int pc = 0; pc < 4; ++pc) {
      const int c = tid + pc * 256;
      const int kr = c >> 4, kcol = c & 15;
      *(bf16x8*)(KsB + ((kr * 256 + kcol * 16) ^ ((kr & 15) << 4))) = kreg[pc];
      const int vr = c >> 3, vcol = c & 7;
      *(bf16x8*)(VsB + ((vr * 128 + vcol * 16) ^ ((vr & 7) << 4))) = vreg[pc];
    }
  };

  stage_load(0);
  stage_write();
  __syncthreads();

  for (int it = 0; it < 32; ++it) {
    if (it < 31) stage_load((it + 1) * 64);

    f32x16 sa = {}, sb = {};
    __builtin_amdgcn_s_setprio(1);
#pragma unroll
    for (int dc = 0; dc < 8; ++dc) {
      const int colb = dc * 32 + hi * 16;
      bf16x8 ka = *(const bf16x8*)(KsB + ((l31 * 256 + colb) ^ ((l31 & 15) << 4)));
      bf16x8 kb = *(const bf16x8*)(KsB + (((32 + l31) * 256 + colb) ^ ((l31 & 15) << 4)));
      sa = __builtin_amdgcn_mfma_f32_32x32x16_bf16(ka, qf[dc], sa, 0, 0, 0);
      sb = __builtin_amdgcn_mfma_f32_32x32x16_bf16(kb, qf[dc], sb, 0, 0, 0);
    }
    __builtin_amdgcn_s_setprio(0);

    float mt;
    {
      float a0 = fmaxf(fmaxf(sa[0], sa[1]), fmaxf(sa[2], sa[3]));
      float a1 = fmaxf(fmaxf(sa[4], sa[5]), fmaxf(sa[6], sa[7]));
      float a2 = fmaxf(fmaxf(sa[8], sa[9]), fmaxf(sa[10], sa[11]));
      float a3 = fmaxf(fmaxf(sa[12], sa[13]), fmaxf(sa[14], sa[15]));
      float b0 = fmaxf(fmaxf(sb[0], sb[1]), fmaxf(sb[2], sb[3]));
      float b1 = fmaxf(fmaxf(sb[4], sb[5]), fmaxf(sb[6], sb[7]));
      float b2 = fmaxf(fmaxf(sb[8], sb[9]), fmaxf(sb[10], sb[11]));
      float b3 = fmaxf(fmaxf(sb[12], sb[13]), fmaxf(sb[14], sb[15]));
      mt = fmaxf(fmaxf(fmaxf(a0, a1), fmaxf(a2, a3)),
                 fmaxf(fmaxf(b0, b1), fmaxf(b2, b3)));
      mt = xhalf_max(mt);
    }
    if (!__all(mt - m <= 8.0f)) {
      const float mn = fmaxf(m, mt);
      const float al = __builtin_amdgcn_exp2f(m - mn);
      m = mn;
      lsum *= al;
#pragma unroll
      for (int dt = 0; dt < 4; ++dt)
#pragma unroll
        for (int i = 0; i < 16; ++i) oacc[dt][i] *= al;
    }
#pragma unroll
    for (int i = 0; i < 16; ++i) sa[i] = __builtin_amdgcn_exp2f(sa[i] - m);
#pragma unroll
    for (int i = 0; i < 16; ++i) sb[i] = __builtin_amdgcn_exp2f(sb[i] - m);
    float r0 = 0.f, r1 = 0.f, r2 = 0.f, r3 = 0.f;
#pragma unroll
    for (int i = 0; i < 4; ++i) {
      r0 += sa[i]; r1 += sa[4 + i]; r2 += sa[8 + i]; r3 += sa[12 + i];
    }
#pragma unroll
    for (int i = 0; i < 4; ++i) {
      r0 += sb[i]; r1 += sb[4 + i]; r2 += sb[8 + i]; r3 += sb[12 + i];
    }
    lsum += xhalf_sum((r0 + r1) + (r2 + r3));

    bf16x8 pf[4];
    pf[0] = build_pfrag<0>(sa);
    pf[1] = build_pfrag<2>(sa);
    pf[2] = build_pfrag<0>(sb);
    pf[3] = build_pfrag<2>(sb);

    __builtin_amdgcn_s_setprio(1);
#pragma unroll
    for (int dt = 0; dt < 4; ++dt) {
      const int d = dt * 32 + l31;
#pragma unroll
      for (int c = 0; c < 4; ++c) {
        bf16x8 vf = *(const bf16x8*)(VsB + ((d * 128 + c * 32 + hi * 16) ^ ((d & 7) << 4)));
        oacc[dt] = __builtin_amdgcn_mfma_f32_32x32x16_bf16(vf, pf[c], oacc[dt], 0, 0, 0);
      }
    }
    __builtin_amdgcn_s_setprio(0);

    __syncthreads();
    if (it < 31) stage_write();
    __syncthreads();
  }

  const float inv = 1.0f / lsum;
  const int t = q0w + l31;
  const size_t obase = (size_t)(b * 256 + (t >> 3)) * 8192 + (t & 7) * 1024 + h * 128;
#pragma unroll
  for (int dt = 0; dt < 4; ++dt) {
#pragma unroll
    for (int g = 0; g < 4; ++g) {
      const int d = dt * 32 + 8 * g + 4 * hi;
      bf16x4 ov;
#pragma unroll
      for (int r = 0; r < 4; ++r) ov[r] = (bf16)(oacc[dt][g * 4 + r] * inv);
      *(bf16x4*)(O2 + obase + d) = ov;
    }
  }
}

extern "C" void kernel_launch(void* const* d_in, const int* in_sizes, int n_in,
                              void* d_out, int out_size, void* d_ws, size_t ws_size,
                              hipStream_t stream) {
  const float* query = (const float*)d_in[0];
  const float* key_ = (const float*)d_in[1];
  const float* value = (const float*)d_in[2];
  const float* Wq = (const float*)d_in[3];
  const float* bq = (const float*)d_in[4];
  const float* Wk = (const float*)d_in[5];
  const float* bk = (const float*)d_in[6];
  const float* Wv = (const float*)d_in[7];
  const float* bv = (const float*)d_in[8];
  const float* Wfc = (const float*)d_in[9];
  const float* bfc = (const float*)d_in[10];
  float* out = (float*)d_out;  // output dtype FLOAT32

  const size_t MB = 1024 * 1024;
  bf16* Qws = (bf16*)d_ws;          // [0,16MB)
  bf16* Kws = Qws + 8 * MB;         // [16,32)
  bf16* Vtw = Kws + 8 * MB;         // [32,48)
  bf16* O2 = Vtw + 8 * MB;          // [48,64)
  float* Pk = (float*)((char*)d_ws + 16 * MB);  // [16,48) after attn

  const float QSC = 1.4426950408889634f / 32.0f;  // log2e / sqrt(HID)
  dim3 blk(256);

  if (ws_size >= (size_t)120 * MB) {
    // FAST PATH: convert to bf16, then global_load_lds GEMMs.
    bf16* Xc = (bf16*)((char*)d_ws + 64 * MB);    // [64,70): 3 x 1M bf16
    bf16* Wc = (bf16*)((char*)d_ws + 70 * MB);    // [70,118): 3 x 8M bf16
    bf16* Wfcc = Qws;                             // reuse Qws after attn

    cvt6<<<dim3(4096, 6), blk, 0, stream>>>(query, key_, value, Wq, Wk, Wv, Xc, Wc);
    qkv_gemm_lds<<<dim3(512, 3), blk, 0, stream>>>(Xc, Wc, bq, bk, bv, Qws, Kws, Vtw, QSC);
    attn_kernel<<<512, blk, 0, stream>>>(Qws, Kws, Vtw, O2);
    cvt1<<<4096, blk, 0, stream>>>(Wfc, Wfcc, 8388608);
    fc_gemm_lds<<<dim3(64, 8), blk, 0, stream>>>(O2, Wfcc, Pk);
    splitk_reduce<<<1024, blk, 0, stream>>>(Pk, bfc, out);
  } else {
    // FALLBACK (round-2 path, fits in 64MB ws).
    qkv_proj<<<dim3(512, 3), blk, 0, stream>>>(query, key_, value, Wq, Wk, Wv,
                                               bq, bk, bv, Qws, Kws, Vtw, QSC);
    attn_kernel<<<512, blk, 0, stream>>>(Qws, Kws, Vtw, O2);
    gemm_fc_f32<<<dim3(64, 8), blk, 0, stream>>>(O2, Wfc, Pk);
    splitk_reduce<<<1024, blk, 0, stream>>>(Pk, bfc, out);
  }
}

// Round 4
// 358.851 us; speedup vs baseline: 1.2953x; 1.0124x over previous
//
#include <hip/hip_runtime.h>
#include <cstdint>
#include <cstddef>

typedef __bf16 bf16;
typedef __bf16 bf16x4 __attribute__((ext_vector_type(4)));
typedef __bf16 bf16x8 __attribute__((ext_vector_type(8)));
typedef float f32x4 __attribute__((ext_vector_type(4)));
typedef float f32x16 __attribute__((ext_vector_type(16)));
typedef unsigned int uint2v __attribute__((ext_vector_type(2)));

#define SLD 40  // fallback GEMM LDS row stride (elements)

// ---------------------------------------------------------------------------
// permlane32_swap helpers (attn softmax cross-half exchange)
// ---------------------------------------------------------------------------
__device__ __forceinline__ void plswap(unsigned& a, unsigned& b) {
  uint2v r = __builtin_amdgcn_permlane32_swap(a, b, false, false);
  a = r[0];
  b = r[1];
}
__device__ __forceinline__ float xhalf_max(float x) {
  unsigned a = __float_as_uint(x), b = a;
  plswap(a, b);
  return fmaxf(__uint_as_float(a), __uint_as_float(b));
}
__device__ __forceinline__ float xhalf_sum(float x) {
  unsigned a = __float_as_uint(x), b = a;
  plswap(a, b);
  return __uint_as_float(a) + __uint_as_float(b);
}
__device__ __forceinline__ unsigned cvtpk(float lo, float hi) {
  unsigned r;
  asm("v_cvt_pk_bf16_f32 %0, %1, %2" : "=v"(r) : "v"(lo), "v"(hi));
  return r;
}

template <int G0>
__device__ __forceinline__ bf16x8 build_pfrag(const f32x16& X) {
  unsigned a0 = cvtpk(X[G0 * 4 + 0], X[G0 * 4 + 1]);
  unsigned b0 = cvtpk(X[G0 * 4 + 4], X[G0 * 4 + 5]);
  plswap(a0, b0);
  unsigned a1 = cvtpk(X[G0 * 4 + 2], X[G0 * 4 + 3]);
  unsigned b1 = cvtpk(X[G0 * 4 + 6], X[G0 * 4 + 7]);
  plswap(a1, b1);
  union {
    unsigned w[4];
    bf16x8 v;
  } u;
  u.w[0] = a0;
  u.w[1] = a1;
  u.w[2] = b0;
  u.w[3] = b1;
  return u.v;
}

// ---------------------------------------------------------------------------
// FAST PATH: f32->bf16 convert pass + global_load_lds GEMMs with a 4-deep
// LDS ring, counted vmcnt, and ONE raw s_barrier per K-step (T3+T4).
// ---------------------------------------------------------------------------
__device__ __forceinline__ void gload16(const bf16* g, bf16* l) {
  __builtin_amdgcn_global_load_lds(
      (const __attribute__((address_space(1))) void*)g,
      (__attribute__((address_space(3))) void*)l, 16, 0, 0);
}

// Convert up to 7 tensors: y<3 -> X (1M f32), y in 3..5 -> Wq/Wk/Wv (8M),
// y==6 -> Wfc (8M, only launched when ws allows upfront conversion).
__global__ __launch_bounds__(256)
void cvt7(const float* __restrict__ x0, const float* __restrict__ x1,
          const float* __restrict__ x2, const float* __restrict__ w0,
          const float* __restrict__ w1, const float* __restrict__ w2,
          const float* __restrict__ w3, bf16* __restrict__ xo,
          bf16* __restrict__ wo, bf16* __restrict__ wfo) {
  const int y = blockIdx.y;
  const float* s;
  bf16* d;
  int n;
  if (y < 3) {
    s = (y == 0) ? x0 : (y == 1) ? x1 : x2;
    d = xo + (size_t)y * 1048576;
    n = 1048576;
  } else if (y < 6) {
    const int z = y - 3;
    s = (z == 0) ? w0 : (z == 1) ? w1 : w2;
    d = wo + (size_t)z * 8388608;
    n = 8388608;
  } else {
    s = w3;
    d = wfo;
    n = 8388608;
  }
  const int i = (blockIdx.x * 256 + threadIdx.x) * 8;
  if (i >= n) return;
  f32x4 a = *(const f32x4*)(s + i);
  f32x4 b = *(const f32x4*)(s + i + 4);
  bf16x8 v;
#pragma unroll
  for (int j = 0; j < 4; ++j) {
    v[j] = (bf16)a[j];
    v[j + 4] = (bf16)b[j];
  }
  *(bf16x8*)(d + i) = v;
}

__global__ __launch_bounds__(256)
void cvt1(const float* __restrict__ s, bf16* __restrict__ d, int n) {
  const int i = (blockIdx.x * 256 + threadIdx.x) * 8;
  if (i >= n) return;
  f32x4 a = *(const f32x4*)(s + i);
  f32x4 b = *(const f32x4*)(s + i + 4);
  bf16x8 v;
#pragma unroll
  for (int j = 0; j < 4; ++j) {
    v[j] = (bf16)a[j];
    v[j + 4] = (bf16)b[j];
  }
  *(bf16x8*)(d + i) = v;
}

// Pipelined K-loop: NT GEMM 128x128 tile, BK=32, global_load_lds staging into
// a 4-buffer LDS ring (linear layout; DMA dest is wave-uniform base+lane*16).
// Schedule per iter t: stage(t+2) -> vmcnt(8) [stage(t) drained, t+1/t+2 in
// flight] -> s_barrier [publishes] -> ds_read+MFMA -> lgkmcnt(0) [ds_reads
// retired before buf[(t+2)&3] can be overwritten after the NEXT barrier].
// WAR safety: stage(t+2) overwrites buf[(t+2)&3], last read at iter t-2,
// separated by barrier(t-1). Requires nt >= 2.
__device__ __forceinline__ void gemm_core_pipe(const bf16* __restrict__ A,
                                               const bf16* __restrict__ B,
                                               bf16* As, bf16* Bs, int K,
                                               int kbeg, int kend, int tm,
                                               int tn, f32x4 (&acc)[4][4]) {
  const int tid = threadIdx.x;
  const int w = tid >> 6, l = tid & 63;
  const int l15 = l & 15, quad = l >> 4;
  const int wm = (w >> 1) << 6, wn = (w & 1) << 6;
  const int rsub = l >> 2, csub = (l & 3) * 8;
  const int nt = (kend - kbeg) >> 5;

  auto stage = [&](int t) {
    const int k0 = kbeg + (t << 5);
    const int buf = (t & 3) * 4096;
#pragma unroll
    for (int c2 = 0; c2 < 2; ++c2) {
      const int c = w * 2 + c2;
      gload16(A + (size_t)(tm + c * 16 + rsub) * K + k0 + csub,
              As + buf + c * 512);
      gload16(B + (size_t)(tn + c * 16 + rsub) * K + k0 + csub,
              Bs + buf + c * 512);
    }
  };

  stage(0);
  stage(1);

  for (int t = 0; t < nt; ++t) {
    if (t + 2 < nt) {
      stage(t + 2);
      asm volatile("s_waitcnt vmcnt(8)" ::: "memory");
    } else if (t + 1 < nt) {
      asm volatile("s_waitcnt vmcnt(4)" ::: "memory");
    } else {
      asm volatile("s_waitcnt vmcnt(0)" ::: "memory");
    }
    __builtin_amdgcn_s_barrier();

    const int buf = (t & 3) * 4096;
    bf16x8 af[4], bfr[4];
#pragma unroll
    for (int i = 0; i < 4; ++i)
      af[i] = *(const bf16x8*)(As + buf + (wm + i * 16 + l15) * 32 + quad * 8);
#pragma unroll
    for (int j = 0; j < 4; ++j)
      bfr[j] = *(const bf16x8*)(Bs + buf + (wn + j * 16 + l15) * 32 + quad * 8);
#pragma unroll
    for (int i = 0; i < 4; ++i)
#pragma unroll
      for (int j = 0; j < 4; ++j)
        acc[i][j] = __builtin_amdgcn_mfma_f32_16x16x32_bf16(af[i], bfr[j],
                                                            acc[i][j], 0, 0, 0);
    asm volatile("s_waitcnt lgkmcnt(0)" ::: "memory");
  }
}

// Fused QKV projection, bf16 inputs. Grid (512, 3); blockIdx.y = slice.
// Scatter layouts:
//   slice 0 (Q): [bh][t][d],   t  = s*8 + c   (osc = qsc)
//   slice 1 (K): [bh][k''][d], k'' = c*256+s  (permuted key order)
//   slice 2 (V): [bh][d][k'']  (V^T, permuted) -> bf16x4 vectorized stores
__global__ __launch_bounds__(256, 2)
void qkv_gemm_lds(const bf16* __restrict__ Xc, const bf16* __restrict__ Wc,
                  const float* __restrict__ Bq, const float* __restrict__ Bk,
                  const float* __restrict__ Bv, bf16* __restrict__ Qo,
                  bf16* __restrict__ Ko, bf16* __restrict__ Vo, float qsc) {
  __shared__ bf16 As[4 * 4096];
  __shared__ bf16 Bs[4 * 4096];
  const int slice = blockIdx.y;
  const bf16* A = Xc + (size_t)slice * 1048576;
  const bf16* B = Wc + (size_t)slice * 8388608;
  const float* bias = (slice == 0) ? Bq : (slice == 1) ? Bk : Bv;
  const int tm = (blockIdx.x >> 6) << 7;  // tiles_n = 64
  const int tn = (blockIdx.x & 63) << 7;

  f32x4 acc[4][4] = {};
  gemm_core_pipe(A, B, As, Bs, 1024, 0, 1024, tm, tn, acc);

  const int tid = threadIdx.x;
  const int w = tid >> 6, l = tid & 63;
  const int l15 = l & 15, quad = l >> 4;
  const int wm = (w >> 1) << 6, wn = (w & 1) << 6;

  if (slice == 2) {
#pragma unroll
    for (int i = 0; i < 4; ++i) {
#pragma unroll
      for (int j = 0; j < 4; ++j) {
        const int n = tn + wn + j * 16 + l15;
        const int d = n & 127, h = (n >> 7) & 7, c = n >> 10;
        const float bv = bias[n];
        const int m0 = tm + wm + i * 16 + quad * 4;
        const int b = m0 >> 8, s0 = m0 & 255;
        const size_t idx = ((size_t)((b * 8 + h) * 128 + d)) * 2048 + (c << 8) + s0;
        bf16x4 ov;
#pragma unroll
        for (int r = 0; r < 4; ++r) ov[r] = (bf16)(acc[i][j][r] + bv);
        *(bf16x4*)(Vo + idx) = ov;
      }
    }
  } else {
    bf16* O = slice ? Ko : Qo;
    const float osc = slice ? 1.0f : qsc;
#pragma unroll
    for (int i = 0; i < 4; ++i) {
#pragma unroll
      for (int j = 0; j < 4; ++j) {
        const int n = tn + wn + j * 16 + l15;
        const int d = n & 127, h = (n >> 7) & 7, c = n >> 10;
        const float bv = bias[n];
#pragma unroll
        for (int r = 0; r < 4; ++r) {
          const int m = tm + wm + i * 16 + quad * 4 + r;
          const int b = m >> 8, s = m & 255;
          const int row = slice ? ((c << 8) | s) : ((s << 3) | c);
          const size_t idx = ((size_t)(b * 8 + h) * 2048 + row) * 128 + d;
          O[idx] = (bf16)((acc[i][j][r] + bv) * osc);
        }
      }
    }
  }
}

// Output projection, split-K x8: A=O2[1024][8192], B=Wfcc[1024][8192] bf16.
// Grid (64, 8): x = 8x8 tiles of 128, y = K-slice of 1024. f32 partials.
__global__ __launch_bounds__(256, 2)
void fc_gemm_lds(const bf16* __restrict__ A, const bf16* __restrict__ B,
                 float* __restrict__ C) {
  __shared__ bf16 As[4 * 4096];
  __shared__ bf16 Bs[4 * 4096];
  const int tm = (blockIdx.x >> 3) << 7;
  const int tn = (blockIdx.x & 7) << 7;
  const int kbeg = blockIdx.y << 10;

  f32x4 acc[4][4] = {};
  gemm_core_pipe(A, B, As, Bs, 8192, kbeg, kbeg + 1024, tm, tn, acc);

  const int tid = threadIdx.x;
  const int w = tid >> 6, l = tid & 63;
  const int l15 = l & 15, quad = l >> 4;
  const int wm = (w >> 1) << 6, wn = (w & 1) << 6;
  const size_t koff = (size_t)blockIdx.y * 1048576;
#pragma unroll
  for (int i = 0; i < 4; ++i) {
#pragma unroll
    for (int j = 0; j < 4; ++j) {
      const int n = tn + wn + j * 16 + l15;
#pragma unroll
      for (int r = 0; r < 4; ++r) {
        const int m = tm + wm + i * 16 + quad * 4 + r;
        C[koff + (size_t)m * 1024 + n] = acc[i][j][r];
      }
    }
  }
}

// ---------------------------------------------------------------------------
// FALLBACK PATH (ws_size < 120MB): round-2 kernels, verified within 64MB ws.
// ---------------------------------------------------------------------------
__global__ __launch_bounds__(256, 4)
void qkv_proj(const float* __restrict__ Xq, const float* __restrict__ Xk,
              const float* __restrict__ Xv, const float* __restrict__ Wq,
              const float* __restrict__ Wk, const float* __restrict__ Wv,
              const float* __restrict__ Bq, const float* __restrict__ Bk,
              const float* __restrict__ Bv, bf16* __restrict__ Qo,
              bf16* __restrict__ Ko, bf16* __restrict__ Vo, float qsc) {
  __shared__ bf16 As[128 * SLD];
  __shared__ bf16 Bs[128 * SLD];
  const int slice = blockIdx.y;
  const float* A = (slice == 0) ? Xq : (slice == 1) ? Xk : Xv;
  const float* W = (slice == 0) ? Wq : (slice == 1) ? Wk : Wv;
  const float* bias = (slice == 0) ? Bq : (slice == 1) ? Bk : Bv;

  const int tid = threadIdx.x;
  const int w = tid >> 6, l = tid & 63;
  const int l15 = l & 15, quad = l >> 4;
  const int tm = (blockIdx.x >> 6) << 7;
  const int tn = (blockIdx.x & 63) << 7;
  const int wm = (w >> 1) << 6;
  const int wn = (w & 1) << 6;

  const int frow = tid >> 1;
  const int fch = (tid & 1) * 16;

  f32x4 acc[4][4] = {};
  f32x4 ar[4], br[4];

  auto load_regs = [&](int k0) {
    const float* sA = A + (size_t)(tm + frow) * 1024 + k0 + fch;
    ar[0] = *(const f32x4*)(sA);
    ar[1] = *(const f32x4*)(sA + 4);
    ar[2] = *(const f32x4*)(sA + 8);
    ar[3] = *(const f32x4*)(sA + 12);
    const float* sB = W + (size_t)(tn + frow) * 1024 + k0 + fch;
    br[0] = *(const f32x4*)(sB);
    br[1] = *(const f32x4*)(sB + 4);
    br[2] = *(const f32x4*)(sB + 8);
    br[3] = *(const f32x4*)(sB + 12);
  };
  auto write_lds = [&]() {
    bf16x8 y0, y1;
#pragma unroll
    for (int j = 0; j < 4; ++j) {
      y0[j] = (bf16)ar[0][j]; y0[j + 4] = (bf16)ar[1][j];
      y1[j] = (bf16)ar[2][j]; y1[j + 4] = (bf16)ar[3][j];
    }
    *(bf16x8*)(As + frow * SLD + fch) = y0;
    *(bf16x8*)(As + frow * SLD + fch + 8) = y1;
#pragma unroll
    for (int j = 0; j < 4; ++j) {
      y0[j] = (bf16)br[0][j]; y0[j + 4] = (bf16)br[1][j];
      y1[j] = (bf16)br[2][j]; y1[j + 4] = (bf16)br[3][j];
    }
    *(bf16x8*)(Bs + frow * SLD + fch) = y0;
    *(bf16x8*)(Bs + frow * SLD + fch + 8) = y1;
  };

  load_regs(0);
  write_lds();
  __syncthreads();

  for (int k0 = 0; k0 < 1024; k0 += 32) {
    const bool more = (k0 + 32) < 1024;
    if (more) load_regs(k0 + 32);

    bf16x8 af[4], bfr[4];
#pragma unroll
    for (int i = 0; i < 4; ++i)
      af[i] = *(const bf16x8*)(As + (wm + i * 16 + l15) * SLD + quad * 8);
#pragma unroll
    for (int j = 0; j < 4; ++j)
      bfr[j] = *(const bf16x8*)(Bs + (wn + j * 16 + l15) * SLD + quad * 8);
#pragma unroll
    for (int i = 0; i < 4; ++i)
#pragma unroll
      for (int j = 0; j < 4; ++j)
        acc[i][j] = __builtin_amdgcn_mfma_f32_16x16x32_bf16(af[i], bfr[j], acc[i][j], 0, 0, 0);

    __syncthreads();
    if (more) {
      write_lds();
      __syncthreads();
    }
  }

  if (slice == 2) {
#pragma unroll
    for (int i = 0; i < 4; ++i) {
#pragma unroll
      for (int j = 0; j < 4; ++j) {
        const int n = tn + wn + j * 16 + l15;
        const int d = n & 127, h = (n >> 7) & 7, c = n >> 10;
        const float bv = bias[n];
        const int m0 = tm + wm + i * 16 + quad * 4;
        const int b = m0 >> 8, s0 = m0 & 255;
        const size_t idx = ((size_t)((b * 8 + h) * 128 + d)) * 2048 + (c << 8) + s0;
        bf16x4 ov;
#pragma unroll
        for (int r = 0; r < 4; ++r) ov[r] = (bf16)(acc[i][j][r] + bv);
        *(bf16x4*)(Vo + idx) = ov;
      }
    }
  } else {
    bf16* O = slice ? Ko : Qo;
    const float osc = slice ? 1.0f : qsc;
#pragma unroll
    for (int i = 0; i < 4; ++i) {
#pragma unroll
      for (int j = 0; j < 4; ++j) {
        const int n = tn + wn + j * 16 + l15;
        const int d = n & 127, h = (n >> 7) & 7, c = n >> 10;
        const float bv = bias[n];
#pragma unroll
        for (int r = 0; r < 4; ++r) {
          const int m = tm + wm + i * 16 + quad * 4 + r;
          const int b = m >> 8, s = m & 255;
          const int row = slice ? ((c << 8) | s) : ((s << 3) | c);
          const size_t idx = ((size_t)(b * 8 + h) * 2048 + row) * 128 + d;
          O[idx] = (bf16)((acc[i][j][r] + bv) * osc);
        }
      }
    }
  }
}

__global__ __launch_bounds__(256, 4)
void gemm_fc_f32(const bf16* __restrict__ Ap, const float* __restrict__ Bp,
                 float* __restrict__ C) {
  __shared__ bf16 As[128 * SLD];
  __shared__ bf16 Bs[128 * SLD];
  const int tid = threadIdx.x;
  const int w = tid >> 6, l = tid & 63;
  const int l15 = l & 15, quad = l >> 4;
  const int tm = (blockIdx.x >> 3) << 7;
  const int tn = (blockIdx.x & 7) << 7;
  const int wm = (w >> 1) << 6;
  const int wn = (w & 1) << 6;
  const int K = 8192;

  f32x4 acc[4][4] = {};
  const int frow = tid >> 1;
  const int fch = (tid & 1) * 16;
  const int kbeg = blockIdx.y << 10;
  const int kend = kbeg + 1024;

  f32x4 brf[4];
  bf16x8 arb[2];

  auto load_regs = [&](int k0) {
#pragma unroll
    for (int pc = 0; pc < 2; ++pc) {
      const int c = tid + pc * 256;
      const int r = c >> 2, col = (c & 3) * 8;
      arb[pc] = *(const bf16x8*)(Ap + (size_t)(tm + r) * K + k0 + col);
    }
    const float* src = Bp + (size_t)(tn + frow) * K + k0 + fch;
    brf[0] = *(const f32x4*)(src);
    brf[1] = *(const f32x4*)(src + 4);
    brf[2] = *(const f32x4*)(src + 8);
    brf[3] = *(const f32x4*)(src + 12);
  };
  auto write_lds = [&]() {
#pragma unroll
    for (int pc = 0; pc < 2; ++pc) {
      const int c = tid + pc * 256;
      const int r = c >> 2, col = (c & 3) * 8;
      *(bf16x8*)(As + r * SLD + col) = arb[pc];
    }
    bf16x8 y0, y1;
#pragma unroll
    for (int j = 0; j < 4; ++j) {
      y0[j] = (bf16)brf[0][j]; y0[j + 4] = (bf16)brf[1][j];
      y1[j] = (bf16)brf[2][j]; y1[j + 4] = (bf16)brf[3][j];
    }
    *(bf16x8*)(Bs + frow * SLD + fch) = y0;
    *(bf16x8*)(Bs + frow * SLD + fch + 8) = y1;
  };

  load_regs(kbeg);
  write_lds();
  __syncthreads();

  for (int k0 = kbeg; k0 < kend; k0 += 32) {
    const bool more = (k0 + 32) < kend;
    if (more) load_regs(k0 + 32);

    bf16x8 af[4], bfr[4];
#pragma unroll
    for (int i = 0; i < 4; ++i)
      af[i] = *(const bf16x8*)(As + (wm + i * 16 + l15) * SLD + quad * 8);
#pragma unroll
    for (int j = 0; j < 4; ++j)
      bfr[j] = *(const bf16x8*)(Bs + (wn + j * 16 + l15) * SLD + quad * 8);
#pragma unroll
    for (int i = 0; i < 4; ++i)
#pragma unroll
      for (int j = 0; j < 4; ++j)
        acc[i][j] = __builtin_amdgcn_mfma_f32_16x16x32_bf16(af[i], bfr[j], acc[i][j], 0, 0, 0);

    __syncthreads();
    if (more) {
      write_lds();
      __syncthreads();
    }
  }

  const size_t koff = (size_t)blockIdx.y * 1048576;
#pragma unroll
  for (int i = 0; i < 4; ++i) {
#pragma unroll
    for (int j = 0; j < 4; ++j) {
      const int n = tn + wn + j * 16 + l15;
#pragma unroll
      for (int r = 0; r < 4; ++r) {
        const int m = tm + wm + i * 16 + quad * 4 + r;
        C[koff + (size_t)m * 1024 + n] = acc[i][j][r];
      }
    }
  }
}

// Sum 8 split-K partials + bias -> f32 out. (shared by both paths)
__global__ __launch_bounds__(256)
void splitk_reduce(const float* __restrict__ P, const float* __restrict__ bias,
                   float* __restrict__ out) {
  const int i = (blockIdx.x * 256 + threadIdx.x) * 4;
  const int n = i & 1023;
  f32x4 s = *(const f32x4*)(bias + n);
#pragma unroll
  for (int kc = 0; kc < 8; ++kc)
    s += *(const f32x4*)(P + (size_t)kc * 1048576 + i);
  *(f32x4*)(out + i) = s;
}

// ---------------------------------------------------------------------------
// Flash attention, 32x32 swapped-operand structure (shared by both paths).
// ---------------------------------------------------------------------------
__global__ __launch_bounds__(256, 2)
void attn_kernel(const bf16* __restrict__ Q, const bf16* __restrict__ Kc,
                 const bf16* __restrict__ Vt, bf16* __restrict__ O2) {
  __shared__ bf16x8 KsV[1024];  // 64 keys x 128 d  (16KB)
  __shared__ bf16x8 VsV[1024];  // 128 d  x 64 keys (16KB)
  char* KsB = (char*)KsV;
  char* VsB = (char*)VsV;

  const int tid = threadIdx.x;
  const int w = tid >> 6, l = tid & 63;
  const int l31 = l & 31, hi = l >> 5;
  const int wg = ((blockIdx.x & 7) << 6) | (blockIdx.x >> 3);
  const int bh = wg >> 4;
  const int qc = wg & 15;
  const int b = bh >> 3, h = bh & 7;
  const int q0w = qc * 128 + w * 32;
  const size_t qkbase = (size_t)bh * 2048 * 128;
  const size_t vbase = (size_t)bh * 128 * 2048;

  bf16x8 qf[8];
#pragma unroll
  for (int dc = 0; dc < 8; ++dc)
    qf[dc] = *(const bf16x8*)(Q + qkbase + (size_t)(q0w + l31) * 128 + dc * 16 + hi * 8);

  f32x16 oacc[4] = {};
  float m = -1e30f, lsum = 0.f;

  bf16x8 kreg[4], vreg[4];
  auto stage_load = [&](int kk) {
#pragma unroll
    for (int pc = 0; pc < 4; ++pc) {
      const int c = tid + pc * 256;
      kreg[pc] = *(const bf16x8*)(Kc + qkbase + (size_t)(kk + (c >> 4)) * 128 + (c & 15) * 8);
      vreg[pc] = *(const bf16x8*)(Vt + vbase + (size_t)(c >> 3) * 2048 + kk + (c & 7) * 8);
    }
  };
  auto stage_write = [&]() {
#pragma unroll
    for (int pc = 0; pc < 4; ++pc) {
      const int c = tid + pc * 256;
      const int kr = c >> 4, kcol = c & 15;
      *(bf16x8*)(KsB + ((kr * 256 + kcol * 16) ^ ((kr & 15) << 4))) = kreg[pc];
      const int vr = c >> 3, vcol = c & 7;
      *(bf16x8*)(VsB + ((vr * 128 + vcol * 16) ^ ((vr & 7) << 4))) = vreg[pc];
    }
  };

  stage_load(0);
  stage_write();
  __syncthreads();

  for (int it = 0; it < 32; ++it) {
    if (it < 31) stage_load((it + 1) * 64);

    f32x16 sa = {}, sb = {};
    __builtin_amdgcn_s_setprio(1);
#pragma unroll
    for (int dc = 0; dc < 8; ++dc) {
      const int colb = dc * 32 + hi * 16;
      bf16x8 ka = *(const bf16x8*)(KsB + ((l31 * 256 + colb) ^ ((l31 & 15) << 4)));
      bf16x8 kb = *(const bf16x8*)(KsB + (((32 + l31) * 256 + colb) ^ ((l31 & 15) << 4)));
      sa = __builtin_amdgcn_mfma_f32_32x32x16_bf16(ka, qf[dc], sa, 0, 0, 0);
      sb = __builtin_amdgcn_mfma_f32_32x32x16_bf16(kb, qf[dc], sb, 0, 0, 0);
    }
    __builtin_amdgcn_s_setprio(0);

    float mt;
    {
      float a0 = fmaxf(fmaxf(sa[0], sa[1]), fmaxf(sa[2], sa[3]));
      float a1 = fmaxf(fmaxf(sa[4], sa[5]), fmaxf(sa[6], sa[7]));
      float a2 = fmaxf(fmaxf(sa[8], sa[9]), fmaxf(sa[10], sa[11]));
      float a3 = fmaxf(fmaxf(sa[12], sa[13]), fmaxf(sa[14], sa[15]));
      float b0 = fmaxf(fmaxf(sb[0], sb[1]), fmaxf(sb[2], sb[3]));
      float b1 = fmaxf(fmaxf(sb[4], sb[5]), fmaxf(sb[6], sb[7]));
      float b2 = fmaxf(fmaxf(sb[8], sb[9]), fmaxf(sb[10], sb[11]));
      float b3 = fmaxf(fmaxf(sb[12], sb[13]), fmaxf(sb[14], sb[15]));
      mt = fmaxf(fmaxf(fmaxf(a0, a1), fmaxf(a2, a3)),
                 fmaxf(fmaxf(b0, b1), fmaxf(b2, b3)));
      mt = xhalf_max(mt);
    }
    if (!__all(mt - m <= 8.0f)) {
      const float mn = fmaxf(m, mt);
      const float al = __builtin_amdgcn_exp2f(m - mn);
      m = mn;
      lsum *= al;
#pragma unroll
      for (int dt = 0; dt < 4; ++dt)
#pragma unroll
        for (int i = 0; i < 16; ++i) oacc[dt][i] *= al;
    }
#pragma unroll
    for (int i = 0; i < 16; ++i) sa[i] = __builtin_amdgcn_exp2f(sa[i] - m);
#pragma unroll
    for (int i = 0; i < 16; ++i) sb[i] = __builtin_amdgcn_exp2f(sb[i] - m);
    float r0 = 0.f, r1 = 0.f, r2 = 0.f, r3 = 0.f;
#pragma unroll
    for (int i = 0; i < 4; ++i) {
      r0 += sa[i]; r1 += sa[4 + i]; r2 += sa[8 + i]; r3 += sa[12 + i];
    }
#pragma unroll
    for (int i = 0; i < 4; ++i) {
      r0 += sb[i]; r1 += sb[4 + i]; r2 += sb[8 + i]; r3 += sb[12 + i];
    }
    lsum += xhalf_sum((r0 + r1) + (r2 + r3));

    bf16x8 pf[4];
    pf[0] = build_pfrag<0>(sa);
    pf[1] = build_pfrag<2>(sa);
    pf[2] = build_pfrag<0>(sb);
    pf[3] = build_pfrag<2>(sb);

    __builtin_amdgcn_s_setprio(1);
#pragma unroll
    for (int dt = 0; dt < 4; ++dt) {
      const int d = dt * 32 + l31;
#pragma unroll
      for (int c = 0; c < 4; ++c) {
        bf16x8 vf = *(const bf16x8*)(VsB + ((d * 128 + c * 32 + hi * 16) ^ ((d & 7) << 4)));
        oacc[dt] = __builtin_amdgcn_mfma_f32_32x32x16_bf16(vf, pf[c], oacc[dt], 0, 0, 0);
      }
    }
    __builtin_amdgcn_s_setprio(0);

    __syncthreads();
    if (it < 31) stage_write();
    __syncthreads();
  }

  const float inv = 1.0f / lsum;
  const int t = q0w + l31;
  const size_t obase = (size_t)(b * 256 + (t >> 3)) * 8192 + (t & 7) * 1024 + h * 128;
#pragma unroll
  for (int dt = 0; dt < 4; ++dt) {
#pragma unroll
    for (int g = 0; g < 4; ++g) {
      const int d = dt * 32 + 8 * g + 4 * hi;
      bf16x4 ov;
#pragma unroll
      for (int r = 0; r < 4; ++r) ov[r] = (bf16)(oacc[dt][g * 4 + r] * inv);
      *(bf16x4*)(O2 + obase + d) = ov;
    }
  }
}

extern "C" void kernel_launch(void* const* d_in, const int* in_sizes, int n_in,
                              void* d_out, int out_size, void* d_ws, size_t ws_size,
                              hipStream_t stream) {
  const float* query = (const float*)d_in[0];
  const float* key_ = (const float*)d_in[1];
  const float* value = (const float*)d_in[2];
  const float* Wq = (const float*)d_in[3];
  const float* bq = (const float*)d_in[4];
  const float* Wk = (const float*)d_in[5];
  const float* bk = (const float*)d_in[6];
  const float* Wv = (const float*)d_in[7];
  const float* bv = (const float*)d_in[8];
  const float* Wfc = (const float*)d_in[9];
  const float* bfc = (const float*)d_in[10];
  float* out = (float*)d_out;  // output dtype FLOAT32

  const size_t MB = 1024 * 1024;
  bf16* Qws = (bf16*)d_ws;          // [0,16MB)
  bf16* Kws = Qws + 8 * MB;         // [16,32)
  bf16* Vtw = Kws + 8 * MB;         // [32,48)
  bf16* O2 = Vtw + 8 * MB;          // [48,64)
  float* Pk = (float*)((char*)d_ws + 16 * MB);  // [16,48) after attn

  const float QSC = 1.4426950408889634f / 32.0f;  // log2e / sqrt(HID)
  dim3 blk(256);

  if (ws_size >= (size_t)136 * MB) {
    // FAST PATH, one upfront convert for all 7 tensors.
    bf16* Xc = (bf16*)((char*)d_ws + 64 * MB);    // [64,70)
    bf16* Wc = (bf16*)((char*)d_ws + 70 * MB);    // [70,118)
    bf16* Wfcc = (bf16*)((char*)d_ws + 118 * MB); // [118,134)

    cvt7<<<dim3(4096, 7), blk, 0, stream>>>(query, key_, value, Wq, Wk, Wv,
                                            Wfc, Xc, Wc, Wfcc);
    qkv_gemm_lds<<<dim3(512, 3), blk, 0, stream>>>(Xc, Wc, bq, bk, bv, Qws, Kws, Vtw, QSC);
    attn_kernel<<<512, blk, 0, stream>>>(Qws, Kws, Vtw, O2);
    fc_gemm_lds<<<dim3(64, 8), blk, 0, stream>>>(O2, Wfcc, Pk);
    splitk_reduce<<<1024, blk, 0, stream>>>(Pk, bfc, out);
  } else if (ws_size >= (size_t)120 * MB) {
    // FAST PATH, Wfc converted after attn into the dead Q region.
    bf16* Xc = (bf16*)((char*)d_ws + 64 * MB);    // [64,70)
    bf16* Wc = (bf16*)((char*)d_ws + 70 * MB);    // [70,118)
    bf16* Wfcc = Qws;                             // reuse Qws after attn

    cvt7<<<dim3(4096, 6), blk, 0, stream>>>(query, key_, value, Wq, Wk, Wv,
                                            Wfc, Xc, Wc, nullptr);
    qkv_gemm_lds<<<dim3(512, 3), blk, 0, stream>>>(Xc, Wc, bq, bk, bv, Qws, Kws, Vtw, QSC);
    attn_kernel<<<512, blk, 0, stream>>>(Qws, Kws, Vtw, O2);
    cvt1<<<4096, blk, 0, stream>>>(Wfc, Wfcc, 8388608);
    fc_gemm_lds<<<dim3(64, 8), blk, 0, stream>>>(O2, Wfcc, Pk);
    splitk_reduce<<<1024, blk, 0, stream>>>(Pk, bfc, out);
  } else {
    // FALLBACK (fits in 64MB ws).
    qkv_proj<<<dim3(512, 3), blk, 0, stream>>>(query, key_, value, Wq, Wk, Wv,
                                               bq, bk, bv, Qws, Kws, Vtw, QSC);
    attn_kernel<<<512, blk, 0, stream>>>(Qws, Kws, Vtw, O2);
    gemm_fc_f32<<<dim3(64, 8), blk, 0, stream>>>(O2, Wfc, Pk);
    splitk_reduce<<<1024, blk, 0, stream>>>(Pk, bfc, out);
  }
}

// Round 6
// 358.814 us; speedup vs baseline: 1.2955x; 1.0001x over previous
//
#include <hip/hip_runtime.h>
#include <cstdint>
#include <cstddef>

typedef __bf16 bf16;
typedef __bf16 bf16x4 __attribute__((ext_vector_type(4)));
typedef __bf16 bf16x8 __attribute__((ext_vector_type(8)));
typedef float f32x4 __attribute__((ext_vector_type(4)));
typedef float f32x16 __attribute__((ext_vector_type(16)));
typedef unsigned int uint2v __attribute__((ext_vector_type(2)));

#define SLD 40  // fallback GEMM LDS row stride (elements)

// ---------------------------------------------------------------------------
// permlane32_swap helpers (attn softmax cross-half exchange)
// ---------------------------------------------------------------------------
__device__ __forceinline__ void plswap(unsigned& a, unsigned& b) {
  uint2v r = __builtin_amdgcn_permlane32_swap(a, b, false, false);
  a = r[0];
  b = r[1];
}
__device__ __forceinline__ float xhalf_max(float x) {
  unsigned a = __float_as_uint(x), b = a;
  plswap(a, b);
  return fmaxf(__uint_as_float(a), __uint_as_float(b));
}
__device__ __forceinline__ float xhalf_sum(float x) {
  unsigned a = __float_as_uint(x), b = a;
  plswap(a, b);
  return __uint_as_float(a) + __uint_as_float(b);
}
__device__ __forceinline__ unsigned cvtpk(float lo, float hi) {
  unsigned r;
  asm("v_cvt_pk_bf16_f32 %0, %1, %2" : "=v"(r) : "v"(lo), "v"(hi));
  return r;
}

template <int G0>
__device__ __forceinline__ bf16x8 build_pfrag(const f32x16& X) {
  unsigned a0 = cvtpk(X[G0 * 4 + 0], X[G0 * 4 + 1]);
  unsigned b0 = cvtpk(X[G0 * 4 + 4], X[G0 * 4 + 5]);
  plswap(a0, b0);
  unsigned a1 = cvtpk(X[G0 * 4 + 2], X[G0 * 4 + 3]);
  unsigned b1 = cvtpk(X[G0 * 4 + 6], X[G0 * 4 + 7]);
  plswap(a1, b1);
  union {
    unsigned w[4];
    bf16x8 v;
  } u;
  u.w[0] = a0;
  u.w[1] = a1;
  u.w[2] = b0;
  u.w[3] = b1;
  return u.v;
}

// ---------------------------------------------------------------------------
// FAST PATH: f32->bf16 convert pass + global_load_lds GEMMs.
// Core v3: 2-buffer LDS ring (32KB total -> 4 blocks/CU), ONE __syncthreads
// per K-step, stage(t+1) issued right AFTER the barrier so the next barrier's
// vmcnt drain waits on loads issued a full MFMA-phase earlier.
// ---------------------------------------------------------------------------
__device__ __forceinline__ void gload16(const bf16* g, bf16* l) {
  __builtin_amdgcn_global_load_lds(
      (const __attribute__((address_space(1))) void*)g,
      (__attribute__((address_space(3))) void*)l, 16, 0, 0);
}

// Convert up to 7 tensors: y<3 -> X (1M f32), y in 3..5 -> Wq/Wk/Wv (8M),
// y==6 -> Wfc (8M, only launched when ws allows upfront conversion).
__global__ __launch_bounds__(256)
void cvt7(const float* __restrict__ x0, const float* __restrict__ x1,
          const float* __restrict__ x2, const float* __restrict__ w0,
          const float* __restrict__ w1, const float* __restrict__ w2,
          const float* __restrict__ w3, bf16* __restrict__ xo,
          bf16* __restrict__ wo, bf16* __restrict__ wfo) {
  const int y = blockIdx.y;
  const float* s;
  bf16* d;
  int n;
  if (y < 3) {
    s = (y == 0) ? x0 : (y == 1) ? x1 : x2;
    d = xo + (size_t)y * 1048576;
    n = 1048576;
  } else if (y < 6) {
    const int z = y - 3;
    s = (z == 0) ? w0 : (z == 1) ? w1 : w2;
    d = wo + (size_t)z * 8388608;
    n = 8388608;
  } else {
    s = w3;
    d = wfo;
    n = 8388608;
  }
  const int i = (blockIdx.x * 256 + threadIdx.x) * 8;
  if (i >= n) return;
  f32x4 a = *(const f32x4*)(s + i);
  f32x4 b = *(const f32x4*)(s + i + 4);
  bf16x8 v;
#pragma unroll
  for (int j = 0; j < 4; ++j) {
    v[j] = (bf16)a[j];
    v[j + 4] = (bf16)b[j];
  }
  *(bf16x8*)(d + i) = v;
}

__global__ __launch_bounds__(256)
void cvt1(const float* __restrict__ s, bf16* __restrict__ d, int n) {
  const int i = (blockIdx.x * 256 + threadIdx.x) * 8;
  if (i >= n) return;
  f32x4 a = *(const f32x4*)(s + i);
  f32x4 b = *(const f32x4*)(s + i + 4);
  bf16x8 v;
#pragma unroll
  for (int j = 0; j < 4; ++j) {
    v[j] = (bf16)a[j];
    v[j + 4] = (bf16)b[j];
  }
  *(bf16x8*)(d + i) = v;
}

// Pipelined K-loop: NT GEMM 128x128 tile, BK=32, global_load_lds staging into
// a 2-buffer LDS ring (linear layout; DMA dest is wave-uniform base+lane*16).
// Iter t: __syncthreads (drains vmcnt: stage(t) published; reads of t-1 are
// already consumed via register deps) -> stage(t+1) into buf[(t+1)&1]
// (overwrites buf(t-1), whose reads finished before this barrier) ->
// ds_read buf[t&1] + 16 MFMA. One barrier per K-step.
__device__ __forceinline__ void gemm_core_pipe(const bf16* __restrict__ A,
                                               const bf16* __restrict__ B,
                                               bf16* As, bf16* Bs, int K,
                                               int kbeg, int kend, int tm,
                                               int tn, f32x4 (&acc)[4][4]) {
  const int tid = threadIdx.x;
  const int w = tid >> 6, l = tid & 63;
  const int l15 = l & 15, quad = l >> 4;
  const int wm = (w >> 1) << 6, wn = (w & 1) << 6;
  const int rsub = l >> 2, csub = (l & 3) * 8;
  const int nt = (kend - kbeg) >> 5;

  auto stage = [&](int t) {
    const int k0 = kbeg + (t << 5);
    const int buf = (t & 1) * 4096;
#pragma unroll
    for (int c2 = 0; c2 < 2; ++c2) {
      const int c = w * 2 + c2;
      gload16(A + (size_t)(tm + c * 16 + rsub) * K + k0 + csub,
              As + buf + c * 512);
      gload16(B + (size_t)(tn + c * 16 + rsub) * K + k0 + csub,
              Bs + buf + c * 512);
    }
  };

  stage(0);

  for (int t = 0; t < nt; ++t) {
    __syncthreads();            // drains vmcnt(0): stage(t) visible to all
    if (t + 1 < nt) stage(t + 1);  // prefetch; drained at NEXT barrier

    const int buf = (t & 1) * 4096;
    bf16x8 af[4], bfr[4];
#pragma unroll
    for (int i = 0; i < 4; ++i)
      af[i] = *(const bf16x8*)(As + buf + (wm + i * 16 + l15) * 32 + quad * 8);
#pragma unroll
    for (int j = 0; j < 4; ++j)
      bfr[j] = *(const bf16x8*)(Bs + buf + (wn + j * 16 + l15) * 32 + quad * 8);
#pragma unroll
    for (int i = 0; i < 4; ++i)
#pragma unroll
      for (int j = 0; j < 4; ++j)
        acc[i][j] = __builtin_amdgcn_mfma_f32_16x16x32_bf16(af[i], bfr[j],
                                                            acc[i][j], 0, 0, 0);
  }
}

// Fused QKV projection, bf16 inputs. Grid (512, 3); blockIdx.y = slice.
// Scatter layouts:
//   slice 0 (Q): [bh][t][d],   t  = s*8 + c   (osc = qsc)
//   slice 1 (K): [bh][k''][d], k'' = c*256+s  (permuted key order)
//   slice 2 (V): [bh][d][k'']  (V^T, permuted) -> bf16x4 vectorized stores
__global__ __launch_bounds__(256, 4)
void qkv_gemm_lds(const bf16* __restrict__ Xc, const bf16* __restrict__ Wc,
                  const float* __restrict__ Bq, const float* __restrict__ Bk,
                  const float* __restrict__ Bv, bf16* __restrict__ Qo,
                  bf16* __restrict__ Ko, bf16* __restrict__ Vo, float qsc) {
  __shared__ bf16 As[2 * 4096];
  __shared__ bf16 Bs[2 * 4096];
  const int slice = blockIdx.y;
  const bf16* A = Xc + (size_t)slice * 1048576;
  const bf16* B = Wc + (size_t)slice * 8388608;
  const float* bias = (slice == 0) ? Bq : (slice == 1) ? Bk : Bv;
  const int tm = (blockIdx.x >> 6) << 7;  // tiles_n = 64
  const int tn = (blockIdx.x & 63) << 7;

  f32x4 acc[4][4] = {};
  gemm_core_pipe(A, B, As, Bs, 1024, 0, 1024, tm, tn, acc);

  const int tid = threadIdx.x;
  const int w = tid >> 6, l = tid & 63;
  const int l15 = l & 15, quad = l >> 4;
  const int wm = (w >> 1) << 6, wn = (w & 1) << 6;

  if (slice == 2) {
#pragma unroll
    for (int i = 0; i < 4; ++i) {
#pragma unroll
      for (int j = 0; j < 4; ++j) {
        const int n = tn + wn + j * 16 + l15;
        const int d = n & 127, h = (n >> 7) & 7, c = n >> 10;
        const float bv = bias[n];
        const int m0 = tm + wm + i * 16 + quad * 4;
        const int b = m0 >> 8, s0 = m0 & 255;
        const size_t idx = ((size_t)((b * 8 + h) * 128 + d)) * 2048 + (c << 8) + s0;
        bf16x4 ov;
#pragma unroll
        for (int r = 0; r < 4; ++r) ov[r] = (bf16)(acc[i][j][r] + bv);
        *(bf16x4*)(Vo + idx) = ov;
      }
    }
  } else {
    bf16* O = slice ? Ko : Qo;
    const float osc = slice ? 1.0f : qsc;
#pragma unroll
    for (int i = 0; i < 4; ++i) {
#pragma unroll
      for (int j = 0; j < 4; ++j) {
        const int n = tn + wn + j * 16 + l15;
        const int d = n & 127, h = (n >> 7) & 7, c = n >> 10;
        const float bv = bias[n];
#pragma unroll
        for (int r = 0; r < 4; ++r) {
          const int m = tm + wm + i * 16 + quad * 4 + r;
          const int b = m >> 8, s = m & 255;
          const int row = slice ? ((c << 8) | s) : ((s << 3) | c);
          const size_t idx = ((size_t)(b * 8 + h) * 2048 + row) * 128 + d;
          O[idx] = (bf16)((acc[i][j][r] + bv) * osc);
        }
      }
    }
  }
}

// Output projection, split-K x8: A=O2[1024][8192], B=Wfcc[1024][8192] bf16.
// Grid (64, 8): x = 8x8 tiles of 128, y = K-slice of 1024. f32 partials.
__global__ __launch_bounds__(256, 4)
void fc_gemm_lds(const bf16* __restrict__ A, const bf16* __restrict__ B,
                 float* __restrict__ C) {
  __shared__ bf16 As[2 * 4096];
  __shared__ bf16 Bs[2 * 4096];
  const int tm = (blockIdx.x >> 3) << 7;
  const int tn = (blockIdx.x & 7) << 7;
  const int kbeg = blockIdx.y << 10;

  f32x4 acc[4][4] = {};
  gemm_core_pipe(A, B, As, Bs, 8192, kbeg, kbeg + 1024, tm, tn, acc);

  const int tid = threadIdx.x;
  const int w = tid >> 6, l = tid & 63;
  const int l15 = l & 15, quad = l >> 4;
  const int wm = (w >> 1) << 6, wn = (w & 1) << 6;
  const size_t koff = (size_t)blockIdx.y * 1048576;
#pragma unroll
  for (int i = 0; i < 4; ++i) {
#pragma unroll
    for (int j = 0; j < 4; ++j) {
      const int n = tn + wn + j * 16 + l15;
#pragma unroll
      for (int r = 0; r < 4; ++r) {
        const int m = tm + wm + i * 16 + quad * 4 + r;
        C[koff + (size_t)m * 1024 + n] = acc[i][j][r];
      }
    }
  }
}

// ---------------------------------------------------------------------------
// FALLBACK PATH (ws_size < 120MB): round-2 kernels, verified within 64MB ws.
// ---------------------------------------------------------------------------
__global__ __launch_bounds__(256, 4)
void qkv_proj(const float* __restrict__ Xq, const float* __restrict__ Xk,
              const float* __restrict__ Xv, const float* __restrict__ Wq,
              const float* __restrict__ Wk, const float* __restrict__ Wv,
              const float* __restrict__ Bq, const float* __restrict__ Bk,
              const float* __restrict__ Bv, bf16* __restrict__ Qo,
              bf16* __restrict__ Ko, bf16* __restrict__ Vo, float qsc) {
  __shared__ bf16 As[128 * SLD];
  __shared__ bf16 Bs[128 * SLD];
  const int slice = blockIdx.y;
  const float* A = (slice == 0) ? Xq : (slice == 1) ? Xk : Xv;
  const float* W = (slice == 0) ? Wq : (slice == 1) ? Wk : Wv;
  const float* bias = (slice == 0) ? Bq : (slice == 1) ? Bk : Bv;

  const int tid = threadIdx.x;
  const int w = tid >> 6, l = tid & 63;
  const int l15 = l & 15, quad = l >> 4;
  const int tm = (blockIdx.x >> 6) << 7;
  const int tn = (blockIdx.x & 63) << 7;
  const int wm = (w >> 1) << 6;
  const int wn = (w & 1) << 6;

  const int frow = tid >> 1;
  const int fch = (tid & 1) * 16;

  f32x4 acc[4][4] = {};
  f32x4 ar[4], br[4];

  auto load_regs = [&](int k0) {
    const float* sA = A + (size_t)(tm + frow) * 1024 + k0 + fch;
    ar[0] = *(const f32x4*)(sA);
    ar[1] = *(const f32x4*)(sA + 4);
    ar[2] = *(const f32x4*)(sA + 8);
    ar[3] = *(const f32x4*)(sA + 12);
    const float* sB = W + (size_t)(tn + frow) * 1024 + k0 + fch;
    br[0] = *(const f32x4*)(sB);
    br[1] = *(const f32x4*)(sB + 4);
    br[2] = *(const f32x4*)(sB + 8);
    br[3] = *(const f32x4*)(sB + 12);
  };
  auto write_lds = [&]() {
    bf16x8 y0, y1;
#pragma unroll
    for (int j = 0; j < 4; ++j) {
      y0[j] = (bf16)ar[0][j]; y0[j + 4] = (bf16)ar[1][j];
      y1[j] = (bf16)ar[2][j]; y1[j + 4] = (bf16)ar[3][j];
    }
    *(bf16x8*)(As + frow * SLD + fch) = y0;
    *(bf16x8*)(As + frow * SLD + fch + 8) = y1;
#pragma unroll
    for (int j = 0; j < 4; ++j) {
      y0[j] = (bf16)br[0][j]; y0[j + 4] = (bf16)br[1][j];
      y1[j] = (bf16)br[2][j]; y1[j + 4] = (bf16)br[3][j];
    }
    *(bf16x8*)(Bs + frow * SLD + fch) = y0;
    *(bf16x8*)(Bs + frow * SLD + fch + 8) = y1;
  };

  load_regs(0);
  write_lds();
  __syncthreads();

  for (int k0 = 0; k0 < 1024; k0 += 32) {
    const bool more = (k0 + 32) < 1024;
    if (more) load_regs(k0 + 32);

    bf16x8 af[4], bfr[4];
#pragma unroll
    for (int i = 0; i < 4; ++i)
      af[i] = *(const bf16x8*)(As + (wm + i * 16 + l15) * SLD + quad * 8);
#pragma unroll
    for (int j = 0; j < 4; ++j)
      bfr[j] = *(const bf16x8*)(Bs + (wn + j * 16 + l15) * SLD + quad * 8);
#pragma unroll
    for (int i = 0; i < 4; ++i)
#pragma unroll
      for (int j = 0; j < 4; ++j)
        acc[i][j] = __builtin_amdgcn_mfma_f32_16x16x32_bf16(af[i], bfr[j], acc[i][j], 0, 0, 0);

    __syncthreads();
    if (more) {
      write_lds();
      __syncthreads();
    }
  }

  if (slice == 2) {
#pragma unroll
    for (int i = 0; i < 4; ++i) {
#pragma unroll
      for (int j = 0; j < 4; ++j) {
        const int n = tn + wn + j * 16 + l15;
        const int d = n & 127, h = (n >> 7) & 7, c = n >> 10;
        const float bv = bias[n];
        const int m0 = tm + wm + i * 16 + quad * 4;
        const int b = m0 >> 8, s0 = m0 & 255;
        const size_t idx = ((size_t)((b * 8 + h) * 128 + d)) * 2048 + (c << 8) + s0;
        bf16x4 ov;
#pragma unroll
        for (int r = 0; r < 4; ++r) ov[r] = (bf16)(acc[i][j][r] + bv);
        *(bf16x4*)(Vo + idx) = ov;
      }
    }
  } else {
    bf16* O = slice ? Ko : Qo;
    const float osc = slice ? 1.0f : qsc;
#pragma unroll
    for (int i = 0; i < 4; ++i) {
#pragma unroll
      for (int j = 0; j < 4; ++j) {
        const int n = tn + wn + j * 16 + l15;
        const int d = n & 127, h = (n >> 7) & 7, c = n >> 10;
        const float bv = bias[n];
#pragma unroll
        for (int r = 0; r < 4; ++r) {
          const int m = tm + wm + i * 16 + quad * 4 + r;
          const int b = m >> 8, s = m & 255;
          const int row = slice ? ((c << 8) | s) : ((s << 3) | c);
          const size_t idx = ((size_t)(b * 8 + h) * 2048 + row) * 128 + d;
          O[idx] = (bf16)((acc[i][j][r] + bv) * osc);
        }
      }
    }
  }
}

__global__ __launch_bounds__(256, 4)
void gemm_fc_f32(const bf16* __restrict__ Ap, const float* __restrict__ Bp,
                 float* __restrict__ C) {
  __shared__ bf16 As[128 * SLD];
  __shared__ bf16 Bs[128 * SLD];
  const int tid = threadIdx.x;
  const int w = tid >> 6, l = tid & 63;
  const int l15 = l & 15, quad = l >> 4;
  const int tm = (blockIdx.x >> 3) << 7;
  const int tn = (blockIdx.x & 7) << 7;
  const int wm = (w >> 1) << 6;
  const int wn = (w & 1) << 6;
  const int K = 8192;

  f32x4 acc[4][4] = {};
  const int frow = tid >> 1;
  const int fch = (tid & 1) * 16;
  const int kbeg = blockIdx.y << 10;
  const int kend = kbeg + 1024;

  f32x4 brf[4];
  bf16x8 arb[2];

  auto load_regs = [&](int k0) {
#pragma unroll
    for (int pc = 0; pc < 2; ++pc) {
      const int c = tid + pc * 256;
      const int r = c >> 2, col = (c & 3) * 8;
      arb[pc] = *(const bf16x8*)(Ap + (size_t)(tm + r) * K + k0 + col);
    }
    const float* src = Bp + (size_t)(tn + frow) * K + k0 + fch;
    brf[0] = *(const f32x4*)(src);
    brf[1] = *(const f32x4*)(src + 4);
    brf[2] = *(const f32x4*)(src + 8);
    brf[3] = *(const f32x4*)(src + 12);
  };
  auto write_lds = [&]() {
#pragma unroll
    for (int pc = 0; pc < 2; ++pc) {
      const int c = tid + pc * 256;
      const int r = c >> 2, col = (c & 3) * 8;
      *(bf16x8*)(As + r * SLD + col) = arb[pc];
    }
    bf16x8 y0, y1;
#pragma unroll
    for (int j = 0; j < 4; ++j) {
      y0[j] = (bf16)brf[0][j]; y0[j + 4] = (bf16)brf[1][j];
      y1[j] = (bf16)brf[2][j]; y1[j + 4] = (bf16)brf[3][j];
    }
    *(bf16x8*)(Bs + frow * SLD + fch) = y0;
    *(bf16x8*)(Bs + frow * SLD + fch + 8) = y1;
  };

  load_regs(kbeg);
  write_lds();
  __syncthreads();

  for (int k0 = kbeg; k0 < kend; k0 += 32) {
    const bool more = (k0 + 32) < kend;
    if (more) load_regs(k0 + 32);

    bf16x8 af[4], bfr[4];
#pragma unroll
    for (int i = 0; i < 4; ++i)
      af[i] = *(const bf16x8*)(As + (wm + i * 16 + l15) * SLD + quad * 8);
#pragma unroll
    for (int j = 0; j < 4; ++j)
      bfr[j] = *(const bf16x8*)(Bs + (wn + j * 16 + l15) * SLD + quad * 8);
#pragma unroll
    for (int i = 0; i < 4; ++i)
#pragma unroll
      for (int j = 0; j < 4; ++j)
        acc[i][j] = __builtin_amdgcn_mfma_f32_16x16x32_bf16(af[i], bfr[j], acc[i][j], 0, 0, 0);

    __syncthreads();
    if (more) {
      write_lds();
      __syncthreads();
    }
  }

  const size_t koff = (size_t)blockIdx.y * 1048576;
#pragma unroll
  for (int i = 0; i < 4; ++i) {
#pragma unroll
    for (int j = 0; j < 4; ++j) {
      const int n = tn + wn + j * 16 + l15;
#pragma unroll
      for (int r = 0; r < 4; ++r) {
        const int m = tm + wm + i * 16 + quad * 4 + r;
        C[koff + (size_t)m * 1024 + n] = acc[i][j][r];
      }
    }
  }
}

// Sum 8 split-K partials + bias -> f32 out. (shared by both paths)
__global__ __launch_bounds__(256)
void splitk_reduce(const float* __restrict__ P, const float* __restrict__ bias,
                   float* __restrict__ out) {
  const int i = (blockIdx.x * 256 + threadIdx.x) * 4;
  const int n = i & 1023;
  f32x4 s = *(const f32x4*)(bias + n);
#pragma unroll
  for (int kc = 0; kc < 8; ++kc)
    s += *(const f32x4*)(P + (size_t)kc * 1048576 + i);
  *(f32x4*)(out + i) = s;
}

// ---------------------------------------------------------------------------
// Flash attention, 32x32 swapped-operand structure. Double-buffered K/V LDS
// (64KB): ONE barrier per K/V tile; stage_write(t+1) slides before it.
// ---------------------------------------------------------------------------
__global__ __launch_bounds__(256, 2)
void attn_kernel(const bf16* __restrict__ Q, const bf16* __restrict__ Kc,
                 const bf16* __restrict__ Vt, bf16* __restrict__ O2) {
  __shared__ bf16x8 KsV[2048];  // 2 x (64 keys x 128 d)  (32KB)
  __shared__ bf16x8 VsV[2048];  // 2 x (128 d  x 64 keys) (32KB)
  char* KsB = (char*)KsV;
  char* VsB = (char*)VsV;

  const int tid = threadIdx.x;
  const int w = tid >> 6, l = tid & 63;
  const int l31 = l & 31, hi = l >> 5;
  const int wg = ((blockIdx.x & 7) << 6) | (blockIdx.x >> 3);
  const int bh = wg >> 4;
  const int qc = wg & 15;
  const int b = bh >> 3, h = bh & 7;
  const int q0w = qc * 128 + w * 32;
  const size_t qkbase = (size_t)bh * 2048 * 128;
  const size_t vbase = (size_t)bh * 128 * 2048;

  bf16x8 qf[8];
#pragma unroll
  for (int dc = 0; dc < 8; ++dc)
    qf[dc] = *(const bf16x8*)(Q + qkbase + (size_t)(q0w + l31) * 128 + dc * 16 + hi * 8);

  f32x16 oacc[4] = {};
  float m = -1e30f, lsum = 0.f;

  bf16x8 kreg[4], vreg[4];
  auto stage_load = [&](int kk) {
#pragma unroll
    for (int pc = 0; pc < 4; ++pc) {
      const int c = tid + pc * 256;
      kreg[pc] = *(const bf16x8*)(Kc + qkbase + (size_t)(kk + (c >> 4)) * 128 + (c & 15) * 8);
      vreg[pc] = *(const bf16x8*)(Vt + vbase + (size_t)(c >> 3) * 2048 + kk + (c & 7) * 8);
    }
  };
  auto stage_write = [&](int buf) {
    const int off = buf << 14;  // 16KB per buffer
#pragma unroll
    for (int pc = 0; pc < 4; ++pc) {
      const int c = tid + pc * 256;
      const int kr = c >> 4, kcol = c & 15;
      *(bf16x8*)(KsB + off + ((kr * 256 + kcol * 16) ^ ((kr & 15) << 4))) = kreg[pc];
      const int vr = c >> 3, vcol = c & 7;
      *(bf16x8*)(VsB + off + ((vr * 128 + vcol * 16) ^ ((vr & 7) << 4))) = vreg[pc];
    }
  };

  stage_load(0);
  stage_write(0);
  __syncthreads();
  int cur = 0;

  for (int it = 0; it < 32; ++it) {
    if (it < 31) stage_load((it + 1) * 64);
    const int koff = cur << 14;

    f32x16 sa = {}, sb = {};
    __builtin_amdgcn_s_setprio(1);
#pragma unroll
    for (int dc = 0; dc < 8; ++dc) {
      const int colb = dc * 32 + hi * 16;
      bf16x8 ka = *(const bf16x8*)(KsB + koff + ((l31 * 256 + colb) ^ ((l31 & 15) << 4)));
      bf16x8 kb = *(const bf16x8*)(KsB + koff + (((32 + l31) * 256 + colb) ^ ((l31 & 15) << 4)));
      sa = __builtin_amdgcn_mfma_f32_32x32x16_bf16(ka, qf[dc], sa, 0, 0, 0);
      sb = __builtin_amdgcn_mfma_f32_32x32x16_bf16(kb, qf[dc], sb, 0, 0, 0);
    }
    __builtin_amdgcn_s_setprio(0);

    float mt;
    {
      float a0 = fmaxf(fmaxf(sa[0], sa[1]), fmaxf(sa[2], sa[3]));
      float a1 = fmaxf(fmaxf(sa[4], sa[5]), fmaxf(sa[6], sa[7]));
      float a2 = fmaxf(fmaxf(sa[8], sa[9]), fmaxf(sa[10], sa[11]));
      float a3 = fmaxf(fmaxf(sa[12], sa[13]), fmaxf(sa[14], sa[15]));
      float b0 = fmaxf(fmaxf(sb[0], sb[1]), fmaxf(sb[2], sb[3]));
      float b1 = fmaxf(fmaxf(sb[4], sb[5]), fmaxf(sb[6], sb[7]));
      float b2 = fmaxf(fmaxf(sb[8], sb[9]), fmaxf(sb[10], sb[11]));
      float b3 = fmaxf(fmaxf(sb[12], sb[13]), fmaxf(sb[14], sb[15]));
      mt = fmaxf(fmaxf(fmaxf(a0, a1), fmaxf(a2, a3)),
                 fmaxf(fmaxf(b0, b1), fmaxf(b2, b3)));
      mt = xhalf_max(mt);
    }
    if (!__all(mt - m <= 8.0f)) {
      const float mn = fmaxf(m, mt);
      const float al = __builtin_amdgcn_exp2f(m - mn);
      m = mn;
      lsum *= al;
#pragma unroll
      for (int dt = 0; dt < 4; ++dt)
#pragma unroll
        for (int i = 0; i < 16; ++i) oacc[dt][i] *= al;
    }
#pragma unroll
    for (int i = 0; i < 16; ++i) sa[i] = __builtin_amdgcn_exp2f(sa[i] - m);
#pragma unroll
    for (int i = 0; i < 16; ++i) sb[i] = __builtin_amdgcn_exp2f(sb[i] - m);
    float r0 = 0.f, r1 = 0.f, r2 = 0.f, r3 = 0.f;
#pragma unroll
    for (int i = 0; i < 4; ++i) {
      r0 += sa[i]; r1 += sa[4 + i]; r2 += sa[8 + i]; r3 += sa[12 + i];
    }
#pragma unroll
    for (int i = 0; i < 4; ++i) {
      r0 += sb[i]; r1 += sb[4 + i]; r2 += sb[8 + i]; r3 += sb[12 + i];
    }
    lsum += xhalf_sum((r0 + r1) + (r2 + r3));

    bf16x8 pf[4];
    pf[0] = build_pfrag<0>(sa);
    pf[1] = build_pfrag<2>(sa);
    pf[2] = build_pfrag<0>(sb);
    pf[3] = build_pfrag<2>(sb);

    __builtin_amdgcn_s_setprio(1);
#pragma unroll
    for (int dt = 0; dt < 4; ++dt) {
      const int d = dt * 32 + l31;
#pragma unroll
      for (int c = 0; c < 4; ++c) {
        bf16x8 vf = *(const bf16x8*)(VsB + koff + ((d * 128 + c * 32 + hi * 16) ^ ((d & 7) << 4)));
        oacc[dt] = __builtin_amdgcn_mfma_f32_32x32x16_bf16(vf, pf[c], oacc[dt], 0, 0, 0);
      }
    }
    __builtin_amdgcn_s_setprio(0);

    if (it < 31) stage_write(cur ^ 1);  // other buffer; safe post barrier(it-1)
    __syncthreads();                    // publish writes; reads of cur done
    cur ^= 1;
  }

  const float inv = 1.0f / lsum;
  const int t = q0w + l31;
  const size_t obase = (size_t)(b * 256 + (t >> 3)) * 8192 + (t & 7) * 1024 + h * 128;
#pragma unroll
  for (int dt = 0; dt < 4; ++dt) {
#pragma unroll
    for (int g = 0; g < 4; ++g) {
      const int d = dt * 32 + 8 * g + 4 * hi;
      bf16x4 ov;
#pragma unroll
      for (int r = 0; r < 4; ++r) ov[r] = (bf16)(oacc[dt][g * 4 + r] * inv);
      *(bf16x4*)(O2 + obase + d) = ov;
    }
  }
}

extern "C" void kernel_launch(void* const* d_in, const int* in_sizes, int n_in,
                              void* d_out, int out_size, void* d_ws, size_t ws_size,
                              hipStream_t stream) {
  const float* query = (const float*)d_in[0];
  const float* key_ = (const float*)d_in[1];
  const float* value = (const float*)d_in[2];
  const float* Wq = (const float*)d_in[3];
  const float* bq = (const float*)d_in[4];
  const float* Wk = (const float*)d_in[5];
  const float* bk = (const float*)d_in[6];
  const float* Wv = (const float*)d_in[7];
  const float* bv = (const float*)d_in[8];
  const float* Wfc = (const float*)d_in[9];
  const float* bfc = (const float*)d_in[10];
  float* out = (float*)d_out;  // output dtype FLOAT32

  const size_t MB = 1024 * 1024;
  bf16* Qws = (bf16*)d_ws;          // [0,16MB)
  bf16* Kws = Qws + 8 * MB;         // [16,32)
  bf16* Vtw = Kws + 8 * MB;         // [32,48)
  bf16* O2 = Vtw + 8 * MB;          // [48,64)
  float* Pk = (float*)((char*)d_ws + 16 * MB);  // [16,48) after attn

  const float QSC = 1.4426950408889634f / 32.0f;  // log2e / sqrt(HID)
  dim3 blk(256);

  if (ws_size >= (size_t)136 * MB) {
    // FAST PATH, one upfront convert for all 7 tensors.
    bf16* Xc = (bf16*)((char*)d_ws + 64 * MB);    // [64,70)
    bf16* Wc = (bf16*)((char*)d_ws + 70 * MB);    // [70,118)
    bf16* Wfcc = (bf16*)((char*)d_ws + 118 * MB); // [118,134)

    cvt7<<<dim3(4096, 7), blk, 0, stream>>>(query, key_, value, Wq, Wk, Wv,
                                            Wfc, Xc, Wc, Wfcc);
    qkv_gemm_lds<<<dim3(512, 3), blk, 0, stream>>>(Xc, Wc, bq, bk, bv, Qws, Kws, Vtw, QSC);
    attn_kernel<<<512, blk, 0, stream>>>(Qws, Kws, Vtw, O2);
    fc_gemm_lds<<<dim3(64, 8), blk, 0, stream>>>(O2, Wfcc, Pk);
    splitk_reduce<<<1024, blk, 0, stream>>>(Pk, bfc, out);
  } else if (ws_size >= (size_t)120 * MB) {
    // FAST PATH, Wfc converted after attn into the dead Q region.
    bf16* Xc = (bf16*)((char*)d_ws + 64 * MB);    // [64,70)
    bf16* Wc = (bf16*)((char*)d_ws + 70 * MB);    // [70,118)
    bf16* Wfcc = Qws;                             // reuse Qws after attn

    cvt7<<<dim3(4096, 6), blk, 0, stream>>>(query, key_, value, Wq, Wk, Wv,
                                            Wfc, Xc, Wc, nullptr);
    qkv_gemm_lds<<<dim3(512, 3), blk, 0, stream>>>(Xc, Wc, bq, bk, bv, Qws, Kws, Vtw, QSC);
    attn_kernel<<<512, blk, 0, stream>>>(Qws, Kws, Vtw, O2);
    cvt1<<<4096, blk, 0, stream>>>(Wfc, Wfcc, 8388608);
    fc_gemm_lds<<<dim3(64, 8), blk, 0, stream>>>(O2, Wfcc, Pk);
    splitk_reduce<<<1024, blk, 0, stream>>>(Pk, bfc, out);
  } else {
    // FALLBACK (fits in 64MB ws).
    qkv_proj<<<dim3(512, 3), blk, 0, stream>>>(query, key_, value, Wq, Wk, Wv,
                                               bq, bk, bv, Qws, Kws, Vtw, QSC);
    attn_kernel<<<512, blk, 0, stream>>>(Qws, Kws, Vtw, O2);
    gemm_fc_f32<<<dim3(64, 8), blk, 0, stream>>>(O2, Wfc, Pk);
    splitk_reduce<<<1024, blk, 0, stream>>>(Pk, bfc, out);
  }
}